// Round 11
// baseline (248.303 us; speedup 1.0000x reference)
//
#include <hip/hip_runtime.h>

typedef __attribute__((ext_vector_type(8))) short short8;
typedef __attribute__((ext_vector_type(4))) short short4_t;
typedef __attribute__((ext_vector_type(4))) float f32x4;
typedef __attribute__((ext_vector_type(2))) unsigned int u32x2;

#define MFMA_B16(a, b, c) __builtin_amdgcn_mfma_f32_16x16x32_bf16((a), (b), (c), 0, 0, 0)

__device__ __forceinline__ unsigned short f2bf(float x) {
    unsigned u = __builtin_bit_cast(unsigned, x);
    u = (u + 0x7FFFu + ((u >> 16) & 1u)) >> 16;
    return (unsigned short)u;
}

__device__ __forceinline__ void load16_lds(const void* g, void* l) {
    __builtin_amdgcn_global_load_lds(
        (const __attribute__((address_space(1))) unsigned int*)g,
        (__attribute__((address_space(3))) unsigned int*)l, 16, 0, 0);
}

// ---------------- multi-tensor fp32 -> bf16 convert (8 elems/thread) --------
__global__ __launch_bounds__(256) void cvt5(
    const float* s0, unsigned short* d0, int n0,
    const float* s1, unsigned short* d1, int n1,
    const float* s2, unsigned short* d2, int n2,
    const float* s3, unsigned short* d3, int n3,
    const float* s4, unsigned short* d4, int n4)
{
    const float* s; unsigned short* d; int n;
    switch (blockIdx.y) {
        case 0:  s = s0; d = d0; n = n0; break;
        case 1:  s = s1; d = d1; n = n1; break;
        case 2:  s = s2; d = d2; n = n2; break;
        case 3:  s = s3; d = d3; n = n3; break;
        default: s = s4; d = d4; n = n4; break;
    }
    const int i = blockIdx.x * 256 + threadIdx.x;
    if (i < n) {
        const float* p = s + (size_t)i * 8;
        f32x4 x0 = *(const f32x4*)p;
        f32x4 x1 = *(const f32x4*)(p + 4);
        short8 r;
#pragma unroll
        for (int j = 0; j < 4; ++j) r[j] = (short)f2bf(x0[j]);
#pragma unroll
        for (int j = 0; j < 4; ++j) r[j + 4] = (short)f2bf(x1[j]);
        *(short8*)(d + (size_t)i * 8) = r;
    }
}

// -- NT GEMM: 128x128 tile, 3-ring counted-vmcnt, XCD remap, chunk-XOR LDS --
// Round-10 addition: the af/wf fragment reads hit rows of stride 64B at a
// fixed 16B chunk -> lanes 0..15 land on 2 bank-groups = 8-way conflict per
// ds_read_b128, likely the real K-step critical path (explains the null
// scheduling grafts of rounds 6/8). Chunk-XOR swizzle: LDS[r][c] holds
// G[r][c ^ (r&3)] (inverse applied on the pre-swizzled GLOBAL source; LDS
// dest stays linear as global_load_lds requires), fragment read chunk =
// quad ^ (row&3) = quad ^ (lanelo&3). 8-way -> 4-way.
struct GemmDesc {
    const unsigned short* A;
    const unsigned short* W;
    const float* bias;
    void* out;
    float scale;
    int mode;   // 0 = bf16 row-major, 1 = V^T per-head [b][h][64][2048], 2 = fp32
};

__global__ __launch_bounds__(256) void gemm128(GemmDesc g0, GemmDesc g1, GemmDesc g2)
{
    constexpr int K = 1024;
    __shared__ union {
        struct { short A[3][128 * 32]; short W[3][128 * 32]; } st;  // 48 KB
        short Lt[128 * 136];                                        // 34.8 KB
    } sm;

    // XCD-chunked bijective remap (requires nwg % 8 == 0; 768 ok)
    const unsigned nwg = gridDim.x * gridDim.y * gridDim.z;
    const unsigned lin = blockIdx.x + gridDim.x * (blockIdx.y + gridDim.y * blockIdx.z);
    const unsigned wl  = (lin & 7u) * (nwg >> 3) + (lin >> 3);
    const unsigned pxy = gridDim.x * gridDim.y;
    const unsigned bz  = wl / pxy;
    const unsigned rm  = wl - bz * pxy;
    const unsigned by  = rm / gridDim.x;
    const unsigned bx  = rm - by * gridDim.x;

    const GemmDesc g = (bz == 0) ? g0 : (bz == 1 ? g1 : g2);
    const int t = threadIdx.x;
    const int lane = t & 63, wave = t >> 6;
    const int lanelo = lane & 15, quad = lane >> 4;
    const int wm = wave >> 1, wn = wave & 1;
    const int bn = bx * 128;
    const int bm = by * 128;

    f32x4 acc[4][4] = {};

    // staging: thread t -> row r0 = t>>2 (and r0+64), chunk t&3; source col
    // pre-swizzled by row&3 so LDS[r][c] = G[r][c^(r&3)].
    const int r0 = t >> 2;
    const int c0 = ((t & 3) ^ (r0 & 3)) * 8;
    const unsigned short* Ag = g.A + (size_t)(bm + r0) * K + c0;
    const unsigned short* Wg = g.W + (size_t)(bn + r0) * K + c0;
    const int qx = (quad ^ (lanelo & 3)) * 8;   // swizzled read chunk

#define STAGE128(k0, buf)                                             \
    do {                                                              \
        short* la_ = sm.st.A[(buf)] + wave * 512;                     \
        short* lw_ = sm.st.W[(buf)] + wave * 512;                     \
        load16_lds(Ag + (k0), la_);                                   \
        load16_lds(Ag + (size_t)64 * K + (k0), la_ + 2048);           \
        load16_lds(Wg + (k0), lw_);                                   \
        load16_lds(Wg + (size_t)64 * K + (k0), lw_ + 2048);           \
    } while (0)

    // prologue: tiles 0 and 1 in flight
    STAGE128(0, 0);
    STAGE128(32, 1);

    int cur = 0;
    for (int k0 = 0; k0 < K; k0 += 32) {
        if (k0 + 32 < K) {
            asm volatile("s_waitcnt vmcnt(4)" ::: "memory");  // tile k0 landed
        } else {
            asm volatile("s_waitcnt vmcnt(0)" ::: "memory");  // last tile
        }
        __builtin_amdgcn_s_barrier();        // all waves: tile-k0 data present,
        asm volatile("" ::: "memory");       // tile-(k0-32) compute finished

        if (k0 + 64 < K) {
            const int nb = (cur + 2 >= 3) ? cur - 1 : cur + 2;
            STAGE128(k0 + 64, nb);           // overwrites tile k0-32 (safe)
        }

        short8 af[4], wf[4];
#pragma unroll
        for (int mt = 0; mt < 4; ++mt)
            af[mt] = *(const short8*)&sm.st.A[cur][(wm * 64 + mt * 16 + lanelo) * 32 + qx];
#pragma unroll
        for (int nt = 0; nt < 4; ++nt)
            wf[nt] = *(const short8*)&sm.st.W[cur][(wn * 64 + nt * 16 + lanelo) * 32 + qx];
#pragma unroll
        for (int mt = 0; mt < 4; ++mt)
#pragma unroll
            for (int nt = 0; nt < 4; ++nt)
                acc[mt][nt] = MFMA_B16(af[mt], wf[nt], acc[mt][nt]);

        asm volatile("" ::: "memory");
        cur = (cur + 1 == 3) ? 0 : cur + 1;
    }
#undef STAGE128

    if (g.mode != 1) {
#pragma unroll
        for (int mt = 0; mt < 4; ++mt) {
#pragma unroll
            for (int nt = 0; nt < 4; ++nt) {
                const int col = bn + wn * 64 + nt * 16 + lanelo;
                const float bs = g.bias[col];
#pragma unroll
                for (int r = 0; r < 4; ++r) {
                    const int row = bm + wm * 64 + mt * 16 + quad * 4 + r;
                    const float val = (acc[mt][nt][r] + bs) * g.scale;
                    if (g.mode == 2)
                        ((float*)g.out)[(size_t)row * K + col] = val;
                    else
                        ((unsigned short*)g.out)[(size_t)row * K + col] = f2bf(val);
                }
            }
        }
    } else {
        __syncthreads();   // staging reads done before Lt (aliases st) is written
#pragma unroll
        for (int mt = 0; mt < 4; ++mt) {
#pragma unroll
            for (int nt = 0; nt < 4; ++nt) {
                const int nl = wn * 64 + nt * 16 + lanelo;
                const float bs = g.bias[bn + nl];
                short4_t pk;
#pragma unroll
                for (int r = 0; r < 4; ++r) pk[r] = (short)f2bf(acc[mt][nt][r] + bs);
                *(short4_t*)&sm.Lt[nl * 136 + wm * 64 + mt * 16 + quad * 4] = pk;
            }
        }
        __syncthreads();
        const int dl = t >> 1;
        const int sb = (t & 1) * 64;
        const int bb = bm >> 11;
        const int s0 = bm & 2047;
        const int hb = bb * 16 + ((bn + dl) >> 6);
        const int dd = (bn + dl) & 63;
        unsigned short* dst = (unsigned short*)g.out +
            ((size_t)hb * 64 + dd) * 2048 + s0 + sb;
#pragma unroll
        for (int j = 0; j < 8; ++j)
            *(short8*)(dst + j * 8) = *(const short8*)&sm.Lt[dl * 136 + sb + j * 8];
    }
}

// -- O-proj GEMM: 64x128 tile, 512 blocks = 2 blocks/CU (was 1) -------------
// Round-10: O-proj's 256-block grid put 1 block/CU = 4 waves/CU -- every
// stall fully exposed. 64x128 tile -> 512 blocks = 2/CU, and the per-K-step
// MFMA phase shortens (8 vs 16) so two blocks interleave. Same 3-ring
// counted-vmcnt protocol (3 stage-calls/wave -> vmcnt(3)), same chunk-XOR
// swizzle, fp32 output with bias.
__global__ __launch_bounds__(256) void gemmO(GemmDesc g)
{
    constexpr int K = 1024;
    __shared__ struct { short A[3][64 * 32]; short W[3][128 * 32]; } sm;  // 36 KB

    const unsigned nwg = gridDim.x * gridDim.y;       // 512, %8==0
    const unsigned lin = blockIdx.x + gridDim.x * blockIdx.y;
    const unsigned wl  = (lin & 7u) * (nwg >> 3) + (lin >> 3);
    const unsigned by  = wl / gridDim.x;
    const unsigned bx  = wl - by * gridDim.x;

    const int t = threadIdx.x;
    const int lane = t & 63, wave = t >> 6;
    const int lanelo = lane & 15, quad = lane >> 4;
    const int bn = bx * 128;
    const int bm = by * 64;

    f32x4 acc[4][2] = {};

    // staging: per wave, 1 A-call (rows wave*16+lr) + 2 W-calls (rows
    // wave*32 + j*16 + lr); chunk lane&3, source col pre-swizzled by row&3.
    const int lr = lane >> 2;                          // 0..15
    const int lc = ((lane & 3) ^ (lr & 3)) * 8;
    const unsigned short* Ag = g.A + (size_t)(bm + wave * 16 + lr) * K + lc;
    const unsigned short* Wg = g.W + (size_t)(bn + wave * 32 + lr) * K + lc;
    const int qx = (quad ^ (lanelo & 3)) * 8;

#define STAGEO(k0, buf)                                               \
    do {                                                              \
        load16_lds(Ag + (k0), sm.A[(buf)] + wave * 512);              \
        load16_lds(Wg + (k0), sm.W[(buf)] + wave * 1024);             \
        load16_lds(Wg + (size_t)16 * K + (k0), sm.W[(buf)] + wave * 1024 + 512); \
    } while (0)

    STAGEO(0, 0);
    STAGEO(32, 1);

    int cur = 0;
    for (int k0 = 0; k0 < K; k0 += 32) {
        if (k0 + 32 < K) {
            asm volatile("s_waitcnt vmcnt(3)" ::: "memory");
        } else {
            asm volatile("s_waitcnt vmcnt(0)" ::: "memory");
        }
        __builtin_amdgcn_s_barrier();
        asm volatile("" ::: "memory");

        if (k0 + 64 < K) {
            const int nb = (cur + 2 >= 3) ? cur - 1 : cur + 2;
            STAGEO(k0 + 64, nb);
        }

        short8 af[4], wf[2];
#pragma unroll
        for (int mt = 0; mt < 4; ++mt)
            af[mt] = *(const short8*)&sm.A[cur][(mt * 16 + lanelo) * 32 + qx];
#pragma unroll
        for (int nt = 0; nt < 2; ++nt)
            wf[nt] = *(const short8*)&sm.W[cur][(wave * 32 + nt * 16 + lanelo) * 32 + qx];
#pragma unroll
        for (int mt = 0; mt < 4; ++mt)
#pragma unroll
            for (int nt = 0; nt < 2; ++nt)
                acc[mt][nt] = MFMA_B16(af[mt], wf[nt], acc[mt][nt]);

        asm volatile("" ::: "memory");
        cur = (cur + 1 == 3) ? 0 : cur + 1;
    }
#undef STAGEO

#pragma unroll
    for (int mt = 0; mt < 4; ++mt) {
#pragma unroll
        for (int nt = 0; nt < 2; ++nt) {
            const int col = bn + wave * 32 + nt * 16 + lanelo;
            const float bs = g.bias[col];
#pragma unroll
            for (int r = 0; r < 4; ++r) {
                const int row = bm + mt * 16 + quad * 4 + r;
                ((float*)g.out)[(size_t)row * K + col] = acc[mt][nt][r] + bs;
            }
        }
    }
}

// -- flash attention: Q-split 4-wave, LDS K/V, swapped softmax, XCD remap ----
// (reverted to the round-9 body -- the round-10 l-via-MFMA was a 1.6us
// regression: the removed VALU wasn't on the critical path and the extra
// MFMAs lengthened the serial QK->P->PV chain. 80.3us verified.)
__global__ __launch_bounds__(256) void attn_flash(
    const unsigned short* __restrict__ Qs,
    const unsigned short* __restrict__ Ks,
    const unsigned short* __restrict__ Vt,
    unsigned short* __restrict__ Op)
{
    constexpr int S = 2048, D = 1024;
    __shared__ short Kb[2][64 * 64];   // [buf][key][d-swizzled]  8 KB each
    __shared__ short Vb[2][64 * 64];   // [buf][d][key-swizzled]  8 KB each
    __shared__ short Pl[4][32 * 72];   // per-wave P tile [32 q][64 key]

    const int tid    = threadIdx.x;
    const int lane   = tid & 63;
    const int wave   = tid >> 6;          // Q-split slot 0..3
    const int lanelo = lane & 15;
    const int quad   = lane >> 4;

    // XCD-chunked bijective remap: grid (16,32) -> XCD c owns heads [4c,4c+4)
    const unsigned lin = blockIdx.x + 16u * blockIdx.y;
    const unsigned wl  = (lin & 7u) * 64u + (lin >> 3);
    const int qt = (int)(wl & 15u);       // 0..15 (128 q-rows per block)
    const int bh = (int)(wl >> 4);        // 0..31
    const int b  = bh >> 4;
    const int h  = bh & 15;
    const size_t base = (size_t)b * S * D + (size_t)h * 64;
    const unsigned short* Vh = Vt + (size_t)bh * 64 * S;
    short* Plw = Pl[wave];
    const int qrow0 = qt * 128 + wave * 32;

    short8 aq[2][2];
#pragma unroll
    for (int mt = 0; mt < 2; ++mt)
#pragma unroll
        for (int ks = 0; ks < 2; ++ks)
            aq[mt][ks] = *(const short8*)(Qs + base +
                (size_t)(qrow0 + mt * 16 + lanelo) * D + ks * 32 + quad * 8);

    f32x4 oacc[2][4] = {};
    float lac[2] = {0.0f, 0.0f};          // per-lane partial l for q=mt*16+lanelo

    const int lr = lane >> 3;
    const int lc = (((lane & 7) ^ lr) * 8);
    const unsigned short* kg = Ks + base + (size_t)(wave * 16 + lr) * D + lc;
    const unsigned short* vg = Vh + (size_t)(wave * 16 + lr) * S + lc;

#pragma unroll
    for (int i = 0; i < 2; ++i) {
        load16_lds(kg + (size_t)(i * 8) * D, &Kb[0][(wave * 2 + i) * 512]);
        load16_lds(vg + (size_t)(i * 8) * S, &Vb[0][(wave * 2 + i) * 512]);
    }
    __syncthreads();

    int cur = 0;
    for (int kt = 0; kt < 32; ++kt) {
        if (kt < 31) {
            const unsigned short* kgn = kg + (size_t)(kt + 1) * 64 * D;
            const unsigned short* vgn = vg + (kt + 1) * 64;
#pragma unroll
            for (int i = 0; i < 2; ++i) {
                load16_lds(kgn + (size_t)(i * 8) * D, &Kb[cur ^ 1][(wave * 2 + i) * 512]);
                load16_lds(vgn + (size_t)(i * 8) * S, &Vb[cur ^ 1][(wave * 2 + i) * 512]);
            }
        }

        short8 kfr[2][4];
#pragma unroll
        for (int ks = 0; ks < 2; ++ks)
#pragma unroll
            for (int nk = 0; nk < 4; ++nk) {
                const int k = nk * 16 + lanelo;
                kfr[ks][nk] = *(const short8*)&Kb[cur][k * 64 +
                    ((ks * 32 + quad * 8) ^ ((k & 7) << 3))];
            }

        f32x4 sv[2][4] = {};
        __builtin_amdgcn_s_setprio(1);
#pragma unroll
        for (int ks = 0; ks < 2; ++ks)
#pragma unroll
            for (int mt = 0; mt < 2; ++mt)
#pragma unroll
                for (int nt = 0; nt < 4; ++nt)
                    sv[mt][nt] = MFMA_B16(kfr[ks][nt], aq[mt][ks], sv[mt][nt]);
        __builtin_amdgcn_s_setprio(0);

#pragma unroll
        for (int mt = 0; mt < 2; ++mt)
#pragma unroll
            for (int nt = 0; nt < 4; ++nt) {
                unsigned u[4];
#pragma unroll
                for (int r = 0; r < 4; ++r) {
                    const float p = exp2f(sv[mt][nt][r]);
                    const unsigned tr = __builtin_bit_cast(unsigned, p) & 0xFFFF0000u;
                    lac[mt] += __builtin_bit_cast(float, tr);
                    u[r] = tr;
                }
                u32x2 pk;
                pk[0] = __builtin_amdgcn_perm(u[1], u[0], 0x07060302u);
                pk[1] = __builtin_amdgcn_perm(u[3], u[2], 0x07060302u);
                *(u32x2*)&Plw[(mt * 16 + lanelo) * 72 + nt * 16 + quad * 4] = pk;
            }

        __builtin_amdgcn_wave_barrier();

        __builtin_amdgcn_s_setprio(1);
#pragma unroll
        for (int ks = 0; ks < 2; ++ks) {
            short8 vfr[4];
#pragma unroll
            for (int nt = 0; nt < 4; ++nt) {
                const int d = nt * 16 + lanelo;
                vfr[nt] = *(const short8*)&Vb[cur][d * 64 +
                    ((ks * 32 + quad * 8) ^ ((d & 7) << 3))];
            }
            short8 ap[2];
#pragma unroll
            for (int mt = 0; mt < 2; ++mt)
                ap[mt] = *(const short8*)&Plw[(mt * 16 + lanelo) * 72 + ks * 32 + quad * 8];
#pragma unroll
            for (int mt = 0; mt < 2; ++mt)
#pragma unroll
                for (int nt = 0; nt < 4; ++nt)
                    oacc[mt][nt] = MFMA_B16(ap[mt], vfr[nt], oacc[mt][nt]);
        }
        __builtin_amdgcn_s_setprio(0);

        if (kt < 31) {
            __syncthreads();
            cur ^= 1;
        }
    }

    float lfull[2];
#pragma unroll
    for (int mt = 0; mt < 2; ++mt) {
        float l = lac[mt];
        l += __shfl_xor(l, 16);
        l += __shfl_xor(l, 32);
        lfull[mt] = l;
    }

#pragma unroll
    for (int mt = 0; mt < 2; ++mt)
#pragma unroll
        for (int r = 0; r < 4; ++r) {
            const float inv = 1.0f / __shfl(lfull[mt], quad * 4 + r);
            const int row = qrow0 + mt * 16 + quad * 4 + r;
#pragma unroll
            for (int nt = 0; nt < 4; ++nt)
                Op[base + (size_t)row * D + nt * 16 + lanelo] = f2bf(oacc[mt][nt][r] * inv);
        }
}

extern "C" void kernel_launch(void* const* d_in, const int* in_sizes, int n_in,
                              void* d_out, int out_size, void* d_ws, size_t ws_size,
                              hipStream_t stream) {
    const float* q   = (const float*)d_in[0];
    const float* k   = (const float*)d_in[1];
    const float* v   = (const float*)d_in[2];
    const float* W_q = (const float*)d_in[3];
    const float* b_q = (const float*)d_in[4];
    const float* W_k = (const float*)d_in[5];
    const float* b_k = (const float*)d_in[6];
    const float* W_v = (const float*)d_in[7];
    const float* b_v = (const float*)d_in[8];
    const float* W_o = (const float*)d_in[9];
    const float* b_o = (const float*)d_in[10];

    constexpr size_t M4 = (size_t)4 * 1024 * 1024;
    constexpr size_t M1 = (size_t)1024 * 1024;

    unsigned short* ob   = (unsigned short*)d_out;
    unsigned short* qb16 = ob;                 // [0,4M)
    unsigned short* wq16 = ob + M4;            // [4M,5M)
    unsigned short* wk16 = ob + M4 + M1;       // [5M,6M)
    unsigned short* wv16 = ob + M4 + 2 * M1;   // [6M,7M)
    unsigned short* d0   = (unsigned short*)d_in[0];
    unsigned short* d1   = (unsigned short*)d_in[1];
    unsigned short* d2   = (unsigned short*)d_in[2];
    unsigned short* kb16 = d0;                 // k bf16 (q fp32 dead after cvtA)
    unsigned short* vb16 = d0 + M4;            // v bf16
    unsigned short* wo16 = (unsigned short*)d_in[3];  // W_o bf16 over W_q fp32
                                               // (dead after cvtA; cvtB is
                                               // stream-ordered after cvtA)
    unsigned short* Qst  = d1;                 // Q stage
    unsigned short* Kst  = d1 + M4;            // K stage
    unsigned short* Vts  = d2;                 // V^T stage
    unsigned short* Ob16 = d2 + M4;            // O stage
    float*          outp = (float*)d_out;

    const dim3 blk(256, 1, 1);
    const int n4 = (int)(M4 / 8), n1 = (int)(M1 / 8);
    const float QSCALE = 0.18033688f;    // 0.125 * log2(e)

    cvt5<<<dim3(2048, 4, 1), blk, 0, stream>>>(
        q, qb16, n4,  W_q, wq16, n1,  W_k, wk16, n1,  W_v, wv16, n1,
        (const float*)nullptr, (unsigned short*)nullptr, 0);
    cvt5<<<dim3(2048, 3, 1), blk, 0, stream>>>(
        k, kb16, n4,  v, vb16, n4,  W_o, wo16, n1,
        nullptr, nullptr, 0, nullptr, nullptr, 0);
    {
        GemmDesc gq{qb16, wq16, b_q, Qst, QSCALE, 0};
        GemmDesc gk{kb16, wk16, b_k, Kst, 1.0f, 0};
        GemmDesc gv{vb16, wv16, b_v, Vts, 1.0f, 1};
        gemm128<<<dim3(8, 32, 3), blk, 0, stream>>>(gq, gk, gv);
    }
    attn_flash<<<dim3(16, 32, 1), blk, 0, stream>>>(Qst, Kst, Vts, Ob16);
    {
        GemmDesc go{Ob16, wo16, b_o, outp, 1.0f, 2};
        gemmO<<<dim3(8, 64, 1), blk, 0, stream>>>(go);
    }
}

// Round 12
// 240.511 us; speedup vs baseline: 1.0324x; 1.0324x over previous
//
#include <hip/hip_runtime.h>

typedef __attribute__((ext_vector_type(8))) short short8;
typedef __attribute__((ext_vector_type(4))) short short4_t;
typedef __attribute__((ext_vector_type(4))) float f32x4;
typedef __attribute__((ext_vector_type(2))) unsigned int u32x2;

#define MFMA_B16(a, b, c) __builtin_amdgcn_mfma_f32_16x16x32_bf16((a), (b), (c), 0, 0, 0)

__device__ __forceinline__ unsigned short f2bf(float x) {
    unsigned u = __builtin_bit_cast(unsigned, x);
    u = (u + 0x7FFFu + ((u >> 16) & 1u)) >> 16;
    return (unsigned short)u;
}

__device__ __forceinline__ void load16_lds(const void* g, void* l) {
    __builtin_amdgcn_global_load_lds(
        (const __attribute__((address_space(1))) unsigned int*)g,
        (__attribute__((address_space(3))) unsigned int*)l, 16, 0, 0);
}

// ---------------- multi-tensor fp32 -> bf16 convert (8 elems/thread) --------
__global__ __launch_bounds__(256) void cvt5(
    const float* s0, unsigned short* d0, int n0,
    const float* s1, unsigned short* d1, int n1,
    const float* s2, unsigned short* d2, int n2,
    const float* s3, unsigned short* d3, int n3,
    const float* s4, unsigned short* d4, int n4)
{
    const float* s; unsigned short* d; int n;
    switch (blockIdx.y) {
        case 0:  s = s0; d = d0; n = n0; break;
        case 1:  s = s1; d = d1; n = n1; break;
        case 2:  s = s2; d = d2; n = n2; break;
        case 3:  s = s3; d = d3; n = n3; break;
        default: s = s4; d = d4; n = n4; break;
    }
    const int i = blockIdx.x * 256 + threadIdx.x;
    if (i < n) {
        const float* p = s + (size_t)i * 8;
        f32x4 x0 = *(const f32x4*)p;
        f32x4 x1 = *(const f32x4*)(p + 4);
        short8 r;
#pragma unroll
        for (int j = 0; j < 4; ++j) r[j] = (short)f2bf(x0[j]);
#pragma unroll
        for (int j = 0; j < 4; ++j) r[j + 4] = (short)f2bf(x1[j]);
        *(short8*)(d + (size_t)i * 8) = r;
    }
}

// -- NT GEMM: 128x128 tile, 3-ring counted-vmcnt, XCD remap, chunk-XOR LDS --
// (unchanged from round 11; gemm grafts have been null 4x -- frozen)
struct GemmDesc {
    const unsigned short* A;
    const unsigned short* W;
    const float* bias;
    void* out;
    float scale;
    int mode;   // 0 = bf16 row-major, 1 = V^T per-head [b][h][64][2048], 2 = fp32
};

__global__ __launch_bounds__(256) void gemm128(GemmDesc g0, GemmDesc g1, GemmDesc g2)
{
    constexpr int K = 1024;
    __shared__ union {
        struct { short A[3][128 * 32]; short W[3][128 * 32]; } st;  // 48 KB
        short Lt[128 * 136];                                        // 34.8 KB
    } sm;

    // XCD-chunked bijective remap (requires nwg % 8 == 0; 768 ok)
    const unsigned nwg = gridDim.x * gridDim.y * gridDim.z;
    const unsigned lin = blockIdx.x + gridDim.x * (blockIdx.y + gridDim.y * blockIdx.z);
    const unsigned wl  = (lin & 7u) * (nwg >> 3) + (lin >> 3);
    const unsigned pxy = gridDim.x * gridDim.y;
    const unsigned bz  = wl / pxy;
    const unsigned rm  = wl - bz * pxy;
    const unsigned by  = rm / gridDim.x;
    const unsigned bx  = rm - by * gridDim.x;

    const GemmDesc g = (bz == 0) ? g0 : (bz == 1 ? g1 : g2);
    const int t = threadIdx.x;
    const int lane = t & 63, wave = t >> 6;
    const int lanelo = lane & 15, quad = lane >> 4;
    const int wm = wave >> 1, wn = wave & 1;
    const int bn = bx * 128;
    const int bm = by * 128;

    f32x4 acc[4][4] = {};

    const int r0 = t >> 2;
    const int c0 = ((t & 3) ^ (r0 & 3)) * 8;
    const unsigned short* Ag = g.A + (size_t)(bm + r0) * K + c0;
    const unsigned short* Wg = g.W + (size_t)(bn + r0) * K + c0;
    const int qx = (quad ^ (lanelo & 3)) * 8;   // swizzled read chunk

#define STAGE128(k0, buf)                                             \
    do {                                                              \
        short* la_ = sm.st.A[(buf)] + wave * 512;                     \
        short* lw_ = sm.st.W[(buf)] + wave * 512;                     \
        load16_lds(Ag + (k0), la_);                                   \
        load16_lds(Ag + (size_t)64 * K + (k0), la_ + 2048);           \
        load16_lds(Wg + (k0), lw_);                                   \
        load16_lds(Wg + (size_t)64 * K + (k0), lw_ + 2048);           \
    } while (0)

    STAGE128(0, 0);
    STAGE128(32, 1);

    int cur = 0;
    for (int k0 = 0; k0 < K; k0 += 32) {
        if (k0 + 32 < K) {
            asm volatile("s_waitcnt vmcnt(4)" ::: "memory");
        } else {
            asm volatile("s_waitcnt vmcnt(0)" ::: "memory");
        }
        __builtin_amdgcn_s_barrier();
        asm volatile("" ::: "memory");

        if (k0 + 64 < K) {
            const int nb = (cur + 2 >= 3) ? cur - 1 : cur + 2;
            STAGE128(k0 + 64, nb);
        }

        short8 af[4], wf[4];
#pragma unroll
        for (int mt = 0; mt < 4; ++mt)
            af[mt] = *(const short8*)&sm.st.A[cur][(wm * 64 + mt * 16 + lanelo) * 32 + qx];
#pragma unroll
        for (int nt = 0; nt < 4; ++nt)
            wf[nt] = *(const short8*)&sm.st.W[cur][(wn * 64 + nt * 16 + lanelo) * 32 + qx];
#pragma unroll
        for (int mt = 0; mt < 4; ++mt)
#pragma unroll
            for (int nt = 0; nt < 4; ++nt)
                acc[mt][nt] = MFMA_B16(af[mt], wf[nt], acc[mt][nt]);

        asm volatile("" ::: "memory");
        cur = (cur + 1 == 3) ? 0 : cur + 1;
    }
#undef STAGE128

    if (g.mode != 1) {
#pragma unroll
        for (int mt = 0; mt < 4; ++mt) {
#pragma unroll
            for (int nt = 0; nt < 4; ++nt) {
                const int col = bn + wn * 64 + nt * 16 + lanelo;
                const float bs = g.bias[col];
#pragma unroll
                for (int r = 0; r < 4; ++r) {
                    const int row = bm + wm * 64 + mt * 16 + quad * 4 + r;
                    const float val = (acc[mt][nt][r] + bs) * g.scale;
                    if (g.mode == 2)
                        ((float*)g.out)[(size_t)row * K + col] = val;
                    else
                        ((unsigned short*)g.out)[(size_t)row * K + col] = f2bf(val);
                }
            }
        }
    } else {
        __syncthreads();
#pragma unroll
        for (int mt = 0; mt < 4; ++mt) {
#pragma unroll
            for (int nt = 0; nt < 4; ++nt) {
                const int nl = wn * 64 + nt * 16 + lanelo;
                const float bs = g.bias[bn + nl];
                short4_t pk;
#pragma unroll
                for (int r = 0; r < 4; ++r) pk[r] = (short)f2bf(acc[mt][nt][r] + bs);
                *(short4_t*)&sm.Lt[nl * 136 + wm * 64 + mt * 16 + quad * 4] = pk;
            }
        }
        __syncthreads();
        const int dl = t >> 1;
        const int sb = (t & 1) * 64;
        const int bb = bm >> 11;
        const int s0 = bm & 2047;
        const int hb = bb * 16 + ((bn + dl) >> 6);
        const int dd = (bn + dl) & 63;
        unsigned short* dst = (unsigned short*)g.out +
            ((size_t)hb * 64 + dd) * 2048 + s0 + sb;
#pragma unroll
        for (int j = 0; j < 8; ++j)
            *(short8*)(dst + j * 8) = *(const short8*)&sm.Lt[dl * 136 + sb + j * 8];
    }
}

// -- O-proj GEMM: 64x128 tile, 512 blocks (unchanged from round 11) ----------
__global__ __launch_bounds__(256) void gemmO(GemmDesc g)
{
    constexpr int K = 1024;
    __shared__ struct { short A[3][64 * 32]; short W[3][128 * 32]; } sm;  // 36 KB

    const unsigned nwg = gridDim.x * gridDim.y;       // 512, %8==0
    const unsigned lin = blockIdx.x + gridDim.x * blockIdx.y;
    const unsigned wl  = (lin & 7u) * (nwg >> 3) + (lin >> 3);
    const unsigned by  = wl / gridDim.x;
    const unsigned bx  = wl - by * gridDim.x;

    const int t = threadIdx.x;
    const int lane = t & 63, wave = t >> 6;
    const int lanelo = lane & 15, quad = lane >> 4;
    const int bn = bx * 128;
    const int bm = by * 64;

    f32x4 acc[4][2] = {};

    const int lr = lane >> 2;                          // 0..15
    const int lc = ((lane & 3) ^ (lr & 3)) * 8;
    const unsigned short* Ag = g.A + (size_t)(bm + wave * 16 + lr) * K + lc;
    const unsigned short* Wg = g.W + (size_t)(bn + wave * 32 + lr) * K + lc;
    const int qx = (quad ^ (lanelo & 3)) * 8;

#define STAGEO(k0, buf)                                               \
    do {                                                              \
        load16_lds(Ag + (k0), sm.A[(buf)] + wave * 512);              \
        load16_lds(Wg + (k0), sm.W[(buf)] + wave * 1024);             \
        load16_lds(Wg + (size_t)16 * K + (k0), sm.W[(buf)] + wave * 1024 + 512); \
    } while (0)

    STAGEO(0, 0);
    STAGEO(32, 1);

    int cur = 0;
    for (int k0 = 0; k0 < K; k0 += 32) {
        if (k0 + 32 < K) {
            asm volatile("s_waitcnt vmcnt(3)" ::: "memory");
        } else {
            asm volatile("s_waitcnt vmcnt(0)" ::: "memory");
        }
        __builtin_amdgcn_s_barrier();
        asm volatile("" ::: "memory");

        if (k0 + 64 < K) {
            const int nb = (cur + 2 >= 3) ? cur - 1 : cur + 2;
            STAGEO(k0 + 64, nb);
        }

        short8 af[4], wf[2];
#pragma unroll
        for (int mt = 0; mt < 4; ++mt)
            af[mt] = *(const short8*)&sm.A[cur][(mt * 16 + lanelo) * 32 + qx];
#pragma unroll
        for (int nt = 0; nt < 2; ++nt)
            wf[nt] = *(const short8*)&sm.W[cur][(wave * 32 + nt * 16 + lanelo) * 32 + qx];
#pragma unroll
        for (int mt = 0; mt < 4; ++mt)
#pragma unroll
            for (int nt = 0; nt < 2; ++nt)
                acc[mt][nt] = MFMA_B16(af[mt], wf[nt], acc[mt][nt]);

        asm volatile("" ::: "memory");
        cur = (cur + 1 == 3) ? 0 : cur + 1;
    }
#undef STAGEO

#pragma unroll
    for (int mt = 0; mt < 4; ++mt) {
#pragma unroll
        for (int nt = 0; nt < 2; ++nt) {
            const int col = bn + wave * 32 + nt * 16 + lanelo;
            const float bs = g.bias[col];
#pragma unroll
            for (int r = 0; r < 4; ++r) {
                const int row = bm + mt * 16 + quad * 4 + r;
                ((float*)g.out)[(size_t)row * K + col] = acc[mt][nt][r] + bs;
            }
        }
    }
}

// -- flash attention: 8-WAVE Q-split (16 q-rows/wave), LDS-shared K/V -------
// Round-11 post-mortem: attn occupancy 18.6% is grid/VGPR-limited (512 blocks
// x 4 waves = 8 waves/CU). This round: same 512-block grid, same block-shared
// K/V staging, but 8 waves x 16 q-rows (512 threads). Per-wave state halves
// (aq/sv/oacc; ~104 VGPR) and per-wave serial chain halves (8+8 MFMA, 16
// exp2/iter), while the CU now holds 2 blocks x 8 = 16 waves (2x). Staging
// traffic per CU is UNCHANGED (this is what round 1 got wrong: per-wave
// private K/V streams); only per-wave kfr/vfr LDS reads double -- LDS pipe
// has headroom. Swapped QK^T softmax, packed P-writes, XOR swizzles, XCD
// remap all carried over with the mt-dimension removed.
__global__ __launch_bounds__(512) void attn_flash(
    const unsigned short* __restrict__ Qs,
    const unsigned short* __restrict__ Ks,
    const unsigned short* __restrict__ Vt,
    unsigned short* __restrict__ Op)
{
    constexpr int S = 2048, D = 1024;
    __shared__ short Kb[2][64 * 64];   // [buf][key][d-swizzled]  8 KB each
    __shared__ short Vb[2][64 * 64];   // [buf][d][key-swizzled]  8 KB each
    __shared__ short Pl[8][16 * 72];   // per-wave P tile [16 q][64 key]

    const int tid    = threadIdx.x;
    const int lane   = tid & 63;
    const int wave   = tid >> 6;          // Q-split slot 0..7
    const int lanelo = lane & 15;
    const int quad   = lane >> 4;

    // XCD-chunked bijective remap: grid (16,32) -> XCD c owns heads [4c,4c+4)
    const unsigned lin = blockIdx.x + 16u * blockIdx.y;
    const unsigned wl  = (lin & 7u) * 64u + (lin >> 3);
    const int qt = (int)(wl & 15u);       // 0..15 (128 q-rows per block)
    const int bh = (int)(wl >> 4);        // 0..31
    const int b  = bh >> 4;
    const int h  = bh & 15;
    const size_t base = (size_t)b * S * D + (size_t)h * 64;
    const unsigned short* Vh = Vt + (size_t)bh * 64 * S;
    short* Plw = Pl[wave];
    const int qrow0 = qt * 128 + wave * 16;

    short8 aq[2];
#pragma unroll
    for (int ks = 0; ks < 2; ++ks)
        aq[ks] = *(const short8*)(Qs + base +
            (size_t)(qrow0 + lanelo) * D + ks * 32 + quad * 8);

    f32x4 oacc[4] = {};
    float lac = 0.0f;                     // per-lane partial l for q = lanelo

    // staging: wave w stages rows [w*8, w*8+8) of the 64-row tile, one call
    // for K and one for V. lane -> row w*8 + (lane>>3), chunk lane&7; source
    // col pre-swizzled by row&7 (= lane>>3) so LDS[r][c] = G[r][c^(r&7)].
    const int lr = lane >> 3;
    const int lc = (((lane & 7) ^ lr) * 8);
    const unsigned short* kg = Ks + base + (size_t)(wave * 8 + lr) * D + lc;
    const unsigned short* vg = Vh + (size_t)(wave * 8 + lr) * S + lc;

    load16_lds(kg, &Kb[0][wave * 512]);
    load16_lds(vg, &Vb[0][wave * 512]);
    __syncthreads();

    int cur = 0;
    for (int kt = 0; kt < 32; ++kt) {
        if (kt < 31) {
            load16_lds(kg + (size_t)(kt + 1) * 64 * D, &Kb[cur ^ 1][wave * 512]);
            load16_lds(vg + (kt + 1) * 64, &Vb[cur ^ 1][wave * 512]);
        }

        short8 kfr[2][4];
#pragma unroll
        for (int ks = 0; ks < 2; ++ks)
#pragma unroll
            for (int nk = 0; nk < 4; ++nk) {
                const int k = nk * 16 + lanelo;
                kfr[ks][nk] = *(const short8*)&Kb[cur][k * 64 +
                    ((ks * 32 + quad * 8) ^ ((k & 7) << 3))];
            }

        // S'^T = K Q^T (exp2 domain): lane owns q=lanelo, keys nt*16+quad*4+r
        f32x4 sv[4] = {};
        __builtin_amdgcn_s_setprio(1);
#pragma unroll
        for (int ks = 0; ks < 2; ++ks)
#pragma unroll
            for (int nt = 0; nt < 4; ++nt)
                sv[nt] = MFMA_B16(kfr[ks][nt], aq[ks], sv[nt]);
        __builtin_amdgcn_s_setprio(0);

        // p = exp2(s); truncate to bf16 (same value feeds P AND l); pack 4
        // consecutive keys -> one ds_write_b64
#pragma unroll
        for (int nt = 0; nt < 4; ++nt) {
            unsigned u[4];
#pragma unroll
            for (int r = 0; r < 4; ++r) {
                const float p = exp2f(sv[nt][r]);
                const unsigned tr = __builtin_bit_cast(unsigned, p) & 0xFFFF0000u;
                lac += __builtin_bit_cast(float, tr);
                u[r] = tr;
            }
            u32x2 pk;
            pk[0] = __builtin_amdgcn_perm(u[1], u[0], 0x07060302u);
            pk[1] = __builtin_amdgcn_perm(u[3], u[2], 0x07060302u);
            *(u32x2*)&Plw[lanelo * 72 + nt * 16 + quad * 4] = pk;
        }

        __builtin_amdgcn_wave_barrier();   // pin DS order: P writes before reads

        // O += P @ V  (V fragments from LDS, swizzled read)
        __builtin_amdgcn_s_setprio(1);
#pragma unroll
        for (int ks = 0; ks < 2; ++ks) {
            short8 vfr[4];
#pragma unroll
            for (int nt = 0; nt < 4; ++nt) {
                const int d = nt * 16 + lanelo;
                vfr[nt] = *(const short8*)&Vb[cur][d * 64 +
                    ((ks * 32 + quad * 8) ^ ((d & 7) << 3))];
            }
            const short8 ap = *(const short8*)&Plw[lanelo * 72 + ks * 32 + quad * 8];
#pragma unroll
            for (int nt = 0; nt < 4; ++nt)
                oacc[nt] = MFMA_B16(ap, vfr[nt], oacc[nt]);
        }
        __builtin_amdgcn_s_setprio(0);

        __builtin_amdgcn_wave_barrier();   // pin DS order: reads before next writes

        if (kt < 31) {
            __syncthreads();
            cur ^= 1;
        }
    }

    // ---- epilogue: reduce l across quads (q = lanelo), then normalize ----
    float l = lac;
    l += __shfl_xor(l, 16);
    l += __shfl_xor(l, 32);

#pragma unroll
    for (int r = 0; r < 4; ++r) {
        const float inv = 1.0f / __shfl(l, quad * 4 + r);
        const int row = qrow0 + quad * 4 + r;
#pragma unroll
        for (int nt = 0; nt < 4; ++nt)
            Op[base + (size_t)row * D + nt * 16 + lanelo] = f2bf(oacc[nt][r] * inv);
    }
}

extern "C" void kernel_launch(void* const* d_in, const int* in_sizes, int n_in,
                              void* d_out, int out_size, void* d_ws, size_t ws_size,
                              hipStream_t stream) {
    const float* q   = (const float*)d_in[0];
    const float* k   = (const float*)d_in[1];
    const float* v   = (const float*)d_in[2];
    const float* W_q = (const float*)d_in[3];
    const float* b_q = (const float*)d_in[4];
    const float* W_k = (const float*)d_in[5];
    const float* b_k = (const float*)d_in[6];
    const float* W_v = (const float*)d_in[7];
    const float* b_v = (const float*)d_in[8];
    const float* W_o = (const float*)d_in[9];
    const float* b_o = (const float*)d_in[10];

    constexpr size_t M4 = (size_t)4 * 1024 * 1024;
    constexpr size_t M1 = (size_t)1024 * 1024;

    unsigned short* ob   = (unsigned short*)d_out;
    unsigned short* qb16 = ob;                 // [0,4M)
    unsigned short* wq16 = ob + M4;            // [4M,5M)
    unsigned short* wk16 = ob + M4 + M1;       // [5M,6M)
    unsigned short* wv16 = ob + M4 + 2 * M1;   // [6M,7M)
    unsigned short* d0   = (unsigned short*)d_in[0];
    unsigned short* d1   = (unsigned short*)d_in[1];
    unsigned short* d2   = (unsigned short*)d_in[2];
    unsigned short* kb16 = d0;                 // k bf16 (q fp32 dead after cvtA)
    unsigned short* vb16 = d0 + M4;            // v bf16
    unsigned short* wo16 = (unsigned short*)d_in[3];  // W_o bf16 over W_q fp32
                                               // (dead after cvtA; cvtB is
                                               // stream-ordered after cvtA)
    unsigned short* Qst  = d1;                 // Q stage
    unsigned short* Kst  = d1 + M4;            // K stage
    unsigned short* Vts  = d2;                 // V^T stage
    unsigned short* Ob16 = d2 + M4;            // O stage
    float*          outp = (float*)d_out;

    const dim3 blk(256, 1, 1);
    const int n4 = (int)(M4 / 8), n1 = (int)(M1 / 8);
    const float QSCALE = 0.18033688f;    // 0.125 * log2(e)

    cvt5<<<dim3(2048, 4, 1), blk, 0, stream>>>(
        q, qb16, n4,  W_q, wq16, n1,  W_k, wk16, n1,  W_v, wv16, n1,
        (const float*)nullptr, (unsigned short*)nullptr, 0);
    cvt5<<<dim3(2048, 3, 1), blk, 0, stream>>>(
        k, kb16, n4,  v, vb16, n4,  W_o, wo16, n1,
        nullptr, nullptr, 0, nullptr, nullptr, 0);
    {
        GemmDesc gq{qb16, wq16, b_q, Qst, QSCALE, 0};
        GemmDesc gk{kb16, wk16, b_k, Kst, 1.0f, 0};
        GemmDesc gv{vb16, wv16, b_v, Vts, 1.0f, 1};
        gemm128<<<dim3(8, 32, 3), blk, 0, stream>>>(gq, gk, gv);
    }
    attn_flash<<<dim3(16, 32, 1), dim3(512, 1, 1), 0, stream>>>(Qst, Kst, Vts, Ob16);
    {
        GemmDesc go{Ob16, wo16, b_o, outp, 1.0f, 2};
        gemmO<<<dim3(8, 64, 1), blk, 0, stream>>>(go);
    }
}

// Round 13
// 235.026 us; speedup vs baseline: 1.0565x; 1.0233x over previous
//
#include <hip/hip_runtime.h>

typedef __attribute__((ext_vector_type(8))) short short8;
typedef __attribute__((ext_vector_type(4))) short short4_t;
typedef __attribute__((ext_vector_type(4))) float f32x4;
typedef __attribute__((ext_vector_type(2))) unsigned int u32x2;

#define MFMA_B16(a, b, c) __builtin_amdgcn_mfma_f32_16x16x32_bf16((a), (b), (c), 0, 0, 0)

__device__ __forceinline__ unsigned short f2bf(float x) {
    unsigned u = __builtin_bit_cast(unsigned, x);
    u = (u + 0x7FFFu + ((u >> 16) & 1u)) >> 16;
    return (unsigned short)u;
}

__device__ __forceinline__ void load16_lds(const void* g, void* l) {
    __builtin_amdgcn_global_load_lds(
        (const __attribute__((address_space(1))) unsigned int*)g,
        (__attribute__((address_space(3))) unsigned int*)l, 16, 0, 0);
}

// ---------------- multi-tensor fp32 -> bf16 convert (8 elems/thread) --------
__global__ __launch_bounds__(256) void cvt5(
    const float* s0, unsigned short* d0, int n0,
    const float* s1, unsigned short* d1, int n1,
    const float* s2, unsigned short* d2, int n2,
    const float* s3, unsigned short* d3, int n3,
    const float* s4, unsigned short* d4, int n4)
{
    const float* s; unsigned short* d; int n;
    switch (blockIdx.y) {
        case 0:  s = s0; d = d0; n = n0; break;
        case 1:  s = s1; d = d1; n = n1; break;
        case 2:  s = s2; d = d2; n = n2; break;
        case 3:  s = s3; d = d3; n = n3; break;
        default: s = s4; d = d4; n = n4; break;
    }
    const int i = blockIdx.x * 256 + threadIdx.x;
    if (i < n) {
        const float* p = s + (size_t)i * 8;
        f32x4 x0 = *(const f32x4*)p;
        f32x4 x1 = *(const f32x4*)(p + 4);
        short8 r;
#pragma unroll
        for (int j = 0; j < 4; ++j) r[j] = (short)f2bf(x0[j]);
#pragma unroll
        for (int j = 0; j < 4; ++j) r[j + 4] = (short)f2bf(x1[j]);
        *(short8*)(d + (size_t)i * 8) = r;
    }
}

// -- NT GEMM: 128x128 tile, 8 WAVES (was 4), 3-ring counted-vmcnt, XCD remap -
// Round-12 lesson (attn): at fixed tile and fixed staging traffic, doubling
// waves-per-block halves the per-wave serial chain and doubles resident
// waves -- the one axis the four null scheduling grafts never touched.
// Here: 512 threads, wave grid 2M x 4N, each wave 64x32 output (8 MFMA vs 16
// per K-step), staging = 2 global_load_lds calls/wave (512 thr x 16B = one
// full 8KB matrix tile per call) -> steady-state vmcnt(2). LDS unchanged
// (48 KB, 3 blocks/CU) -> 24 waves/CU (was 12). Chunk-XOR swizzle and the
// XCD-chunked remap carried over unchanged.
struct GemmDesc {
    const unsigned short* A;
    const unsigned short* W;
    const float* bias;
    void* out;
    float scale;
    int mode;   // 0 = bf16 row-major, 1 = V^T per-head [b][h][64][2048], 2 = fp32
};

__global__ __launch_bounds__(512) void gemm128(GemmDesc g0, GemmDesc g1, GemmDesc g2)
{
    constexpr int K = 1024;
    __shared__ union {
        struct { short A[3][128 * 32]; short W[3][128 * 32]; } st;  // 48 KB
        short Lt[128 * 136];                                        // 34.8 KB
    } sm;

    // XCD-chunked bijective remap (requires nwg % 8 == 0; 768 ok)
    const unsigned nwg = gridDim.x * gridDim.y * gridDim.z;
    const unsigned lin = blockIdx.x + gridDim.x * (blockIdx.y + gridDim.y * blockIdx.z);
    const unsigned wl  = (lin & 7u) * (nwg >> 3) + (lin >> 3);
    const unsigned pxy = gridDim.x * gridDim.y;
    const unsigned bz  = wl / pxy;
    const unsigned rm  = wl - bz * pxy;
    const unsigned by  = rm / gridDim.x;
    const unsigned bx  = rm - by * gridDim.x;

    const GemmDesc g = (bz == 0) ? g0 : (bz == 1 ? g1 : g2);
    const int t = threadIdx.x;
    const int lane = t & 63, wave = t >> 6;     // wave 0..7
    const int lanelo = lane & 15, quad = lane >> 4;
    const int wm = wave >> 2, wn = wave & 3;    // 2M x 4N wave grid
    const int bn = bx * 128;
    const int bm = by * 128;

    f32x4 acc[4][2] = {};

    // staging: thread t -> row r0 = t>>2 (all 128 rows), chunk t&3; source
    // col pre-swizzled by row&3 so LDS[r][c] = G[r][c^(r&3)].
    const int r0 = t >> 2;
    const int c0 = ((t & 3) ^ (r0 & 3)) * 8;
    const unsigned short* Ag = g.A + (size_t)(bm + r0) * K + c0;
    const unsigned short* Wg = g.W + (size_t)(bn + r0) * K + c0;
    const int qx = (quad ^ (lanelo & 3)) * 8;   // swizzled read chunk

#define STAGE128(k0, buf)                                             \
    do {                                                              \
        load16_lds(Ag + (k0), sm.st.A[(buf)] + wave * 512);           \
        load16_lds(Wg + (k0), sm.st.W[(buf)] + wave * 512);           \
    } while (0)

    STAGE128(0, 0);
    STAGE128(32, 1);

    int cur = 0;
    for (int k0 = 0; k0 < K; k0 += 32) {
        if (k0 + 32 < K) {
            asm volatile("s_waitcnt vmcnt(2)" ::: "memory");  // tile k0 landed
        } else {
            asm volatile("s_waitcnt vmcnt(0)" ::: "memory");  // last tile
        }
        __builtin_amdgcn_s_barrier();        // all waves: tile-k0 data present,
        asm volatile("" ::: "memory");       // tile-(k0-32) compute finished

        if (k0 + 64 < K) {
            const int nb = (cur + 2 >= 3) ? cur - 1 : cur + 2;
            STAGE128(k0 + 64, nb);           // overwrites tile k0-32 (safe)
        }

        short8 af[4], wf[2];
#pragma unroll
        for (int mt = 0; mt < 4; ++mt)
            af[mt] = *(const short8*)&sm.st.A[cur][(wm * 64 + mt * 16 + lanelo) * 32 + qx];
#pragma unroll
        for (int nt = 0; nt < 2; ++nt)
            wf[nt] = *(const short8*)&sm.st.W[cur][(wn * 32 + nt * 16 + lanelo) * 32 + qx];
#pragma unroll
        for (int mt = 0; mt < 4; ++mt)
#pragma unroll
            for (int nt = 0; nt < 2; ++nt)
                acc[mt][nt] = MFMA_B16(af[mt], wf[nt], acc[mt][nt]);

        asm volatile("" ::: "memory");
        cur = (cur + 1 == 3) ? 0 : cur + 1;
    }
#undef STAGE128

    if (g.mode != 1) {
#pragma unroll
        for (int mt = 0; mt < 4; ++mt) {
#pragma unroll
            for (int nt = 0; nt < 2; ++nt) {
                const int col = bn + wn * 32 + nt * 16 + lanelo;
                const float bs = g.bias[col];
#pragma unroll
                for (int r = 0; r < 4; ++r) {
                    const int row = bm + wm * 64 + mt * 16 + quad * 4 + r;
                    const float val = (acc[mt][nt][r] + bs) * g.scale;
                    if (g.mode == 2)
                        ((float*)g.out)[(size_t)row * K + col] = val;
                    else
                        ((unsigned short*)g.out)[(size_t)row * K + col] = f2bf(val);
                }
            }
        }
    } else {
        __syncthreads();   // staging reads done before Lt (aliases st) is written
#pragma unroll
        for (int mt = 0; mt < 4; ++mt) {
#pragma unroll
            for (int nt = 0; nt < 2; ++nt) {
                const int nl = wn * 32 + nt * 16 + lanelo;
                const float bs = g.bias[bn + nl];
                short4_t pk;
#pragma unroll
                for (int r = 0; r < 4; ++r) pk[r] = (short)f2bf(acc[mt][nt][r] + bs);
                *(short4_t*)&sm.Lt[nl * 136 + wm * 64 + mt * 16 + quad * 4] = pk;
            }
        }
        __syncthreads();
        const int dl = t >> 2;              // 0..127: d-index within tile
        const int sb = (t & 3) * 32;        // 32-short chunk of the s-run
        const int bb = bm >> 11;
        const int s0 = bm & 2047;
        const int hb = bb * 16 + ((bn + dl) >> 6);
        const int dd = (bn + dl) & 63;
        unsigned short* dst = (unsigned short*)g.out +
            ((size_t)hb * 64 + dd) * 2048 + s0 + sb;
#pragma unroll
        for (int j = 0; j < 4; ++j)
            *(short8*)(dst + j * 8) = *(const short8*)&sm.Lt[dl * 136 + sb + j * 8];
    }
}

// -- O-proj GEMM: 64x128 tile, 512 blocks (unchanged from round 11) ----------
__global__ __launch_bounds__(256) void gemmO(GemmDesc g)
{
    constexpr int K = 1024;
    __shared__ struct { short A[3][64 * 32]; short W[3][128 * 32]; } sm;  // 36 KB

    const unsigned nwg = gridDim.x * gridDim.y;       // 512, %8==0
    const unsigned lin = blockIdx.x + gridDim.x * blockIdx.y;
    const unsigned wl  = (lin & 7u) * (nwg >> 3) + (lin >> 3);
    const unsigned by  = wl / gridDim.x;
    const unsigned bx  = wl - by * gridDim.x;

    const int t = threadIdx.x;
    const int lane = t & 63, wave = t >> 6;
    const int lanelo = lane & 15, quad = lane >> 4;
    const int bn = bx * 128;
    const int bm = by * 64;

    f32x4 acc[4][2] = {};

    const int lr = lane >> 2;                          // 0..15
    const int lc = ((lane & 3) ^ (lr & 3)) * 8;
    const unsigned short* Ag = g.A + (size_t)(bm + wave * 16 + lr) * K + lc;
    const unsigned short* Wg = g.W + (size_t)(bn + wave * 32 + lr) * K + lc;
    const int qx = (quad ^ (lanelo & 3)) * 8;

#define STAGEO(k0, buf)                                               \
    do {                                                              \
        load16_lds(Ag + (k0), sm.A[(buf)] + wave * 512);              \
        load16_lds(Wg + (k0), sm.W[(buf)] + wave * 1024);             \
        load16_lds(Wg + (size_t)16 * K + (k0), sm.W[(buf)] + wave * 1024 + 512); \
    } while (0)

    STAGEO(0, 0);
    STAGEO(32, 1);

    int cur = 0;
    for (int k0 = 0; k0 < K; k0 += 32) {
        if (k0 + 32 < K) {
            asm volatile("s_waitcnt vmcnt(3)" ::: "memory");
        } else {
            asm volatile("s_waitcnt vmcnt(0)" ::: "memory");
        }
        __builtin_amdgcn_s_barrier();
        asm volatile("" ::: "memory");

        if (k0 + 64 < K) {
            const int nb = (cur + 2 >= 3) ? cur - 1 : cur + 2;
            STAGEO(k0 + 64, nb);
        }

        short8 af[4], wf[2];
#pragma unroll
        for (int mt = 0; mt < 4; ++mt)
            af[mt] = *(const short8*)&sm.A[cur][(mt * 16 + lanelo) * 32 + qx];
#pragma unroll
        for (int nt = 0; nt < 2; ++nt)
            wf[nt] = *(const short8*)&sm.W[cur][(wave * 32 + nt * 16 + lanelo) * 32 + qx];
#pragma unroll
        for (int mt = 0; mt < 4; ++mt)
#pragma unroll
            for (int nt = 0; nt < 2; ++nt)
                acc[mt][nt] = MFMA_B16(af[mt], wf[nt], acc[mt][nt]);

        asm volatile("" ::: "memory");
        cur = (cur + 1 == 3) ? 0 : cur + 1;
    }
#undef STAGEO

#pragma unroll
    for (int mt = 0; mt < 4; ++mt) {
#pragma unroll
        for (int nt = 0; nt < 2; ++nt) {
            const int col = bn + wave * 32 + nt * 16 + lanelo;
            const float bs = g.bias[col];
#pragma unroll
            for (int r = 0; r < 4; ++r) {
                const int row = bm + mt * 16 + quad * 4 + r;
                ((float*)g.out)[(size_t)row * K + col] = acc[mt][nt][r] + bs;
            }
        }
    }
}

// -- flash attention: 8-wave Q-split, LDS-shared K/V (round 12, verified) ----
__global__ __launch_bounds__(512) void attn_flash(
    const unsigned short* __restrict__ Qs,
    const unsigned short* __restrict__ Ks,
    const unsigned short* __restrict__ Vt,
    unsigned short* __restrict__ Op)
{
    constexpr int S = 2048, D = 1024;
    __shared__ short Kb[2][64 * 64];   // [buf][key][d-swizzled]  8 KB each
    __shared__ short Vb[2][64 * 64];   // [buf][d][key-swizzled]  8 KB each
    __shared__ short Pl[8][16 * 72];   // per-wave P tile [16 q][64 key]

    const int tid    = threadIdx.x;
    const int lane   = tid & 63;
    const int wave   = tid >> 6;          // Q-split slot 0..7
    const int lanelo = lane & 15;
    const int quad   = lane >> 4;

    // XCD-chunked bijective remap: grid (16,32) -> XCD c owns heads [4c,4c+4)
    const unsigned lin = blockIdx.x + 16u * blockIdx.y;
    const unsigned wl  = (lin & 7u) * 64u + (lin >> 3);
    const int qt = (int)(wl & 15u);       // 0..15 (128 q-rows per block)
    const int bh = (int)(wl >> 4);        // 0..31
    const int b  = bh >> 4;
    const int h  = bh & 15;
    const size_t base = (size_t)b * S * D + (size_t)h * 64;
    const unsigned short* Vh = Vt + (size_t)bh * 64 * S;
    short* Plw = Pl[wave];
    const int qrow0 = qt * 128 + wave * 16;

    short8 aq[2];
#pragma unroll
    for (int ks = 0; ks < 2; ++ks)
        aq[ks] = *(const short8*)(Qs + base +
            (size_t)(qrow0 + lanelo) * D + ks * 32 + quad * 8);

    f32x4 oacc[4] = {};
    float lac = 0.0f;                     // per-lane partial l for q = lanelo

    const int lr = lane >> 3;
    const int lc = (((lane & 7) ^ lr) * 8);
    const unsigned short* kg = Ks + base + (size_t)(wave * 8 + lr) * D + lc;
    const unsigned short* vg = Vh + (size_t)(wave * 8 + lr) * S + lc;

    load16_lds(kg, &Kb[0][wave * 512]);
    load16_lds(vg, &Vb[0][wave * 512]);
    __syncthreads();

    int cur = 0;
    for (int kt = 0; kt < 32; ++kt) {
        if (kt < 31) {
            load16_lds(kg + (size_t)(kt + 1) * 64 * D, &Kb[cur ^ 1][wave * 512]);
            load16_lds(vg + (kt + 1) * 64, &Vb[cur ^ 1][wave * 512]);
        }

        short8 kfr[2][4];
#pragma unroll
        for (int ks = 0; ks < 2; ++ks)
#pragma unroll
            for (int nk = 0; nk < 4; ++nk) {
                const int k = nk * 16 + lanelo;
                kfr[ks][nk] = *(const short8*)&Kb[cur][k * 64 +
                    ((ks * 32 + quad * 8) ^ ((k & 7) << 3))];
            }

        f32x4 sv[4] = {};
        __builtin_amdgcn_s_setprio(1);
#pragma unroll
        for (int ks = 0; ks < 2; ++ks)
#pragma unroll
            for (int nt = 0; nt < 4; ++nt)
                sv[nt] = MFMA_B16(kfr[ks][nt], aq[ks], sv[nt]);
        __builtin_amdgcn_s_setprio(0);

#pragma unroll
        for (int nt = 0; nt < 4; ++nt) {
            unsigned u[4];
#pragma unroll
            for (int r = 0; r < 4; ++r) {
                const float p = exp2f(sv[nt][r]);
                const unsigned tr = __builtin_bit_cast(unsigned, p) & 0xFFFF0000u;
                lac += __builtin_bit_cast(float, tr);
                u[r] = tr;
            }
            u32x2 pk;
            pk[0] = __builtin_amdgcn_perm(u[1], u[0], 0x07060302u);
            pk[1] = __builtin_amdgcn_perm(u[3], u[2], 0x07060302u);
            *(u32x2*)&Plw[lanelo * 72 + nt * 16 + quad * 4] = pk;
        }

        __builtin_amdgcn_wave_barrier();   // pin DS order: P writes before reads

        __builtin_amdgcn_s_setprio(1);
#pragma unroll
        for (int ks = 0; ks < 2; ++ks) {
            short8 vfr[4];
#pragma unroll
            for (int nt = 0; nt < 4; ++nt) {
                const int d = nt * 16 + lanelo;
                vfr[nt] = *(const short8*)&Vb[cur][d * 64 +
                    ((ks * 32 + quad * 8) ^ ((d & 7) << 3))];
            }
            const short8 ap = *(const short8*)&Plw[lanelo * 72 + ks * 32 + quad * 8];
#pragma unroll
            for (int nt = 0; nt < 4; ++nt)
                oacc[nt] = MFMA_B16(ap, vfr[nt], oacc[nt]);
        }
        __builtin_amdgcn_s_setprio(0);

        __builtin_amdgcn_wave_barrier();   // pin DS order: reads before next writes

        if (kt < 31) {
            __syncthreads();
            cur ^= 1;
        }
    }

    float l = lac;
    l += __shfl_xor(l, 16);
    l += __shfl_xor(l, 32);

#pragma unroll
    for (int r = 0; r < 4; ++r) {
        const float inv = 1.0f / __shfl(l, quad * 4 + r);
        const int row = qrow0 + quad * 4 + r;
#pragma unroll
        for (int nt = 0; nt < 4; ++nt)
            Op[base + (size_t)row * D + nt * 16 + lanelo] = f2bf(oacc[nt][r] * inv);
    }
}

extern "C" void kernel_launch(void* const* d_in, const int* in_sizes, int n_in,
                              void* d_out, int out_size, void* d_ws, size_t ws_size,
                              hipStream_t stream) {
    const float* q   = (const float*)d_in[0];
    const float* k   = (const float*)d_in[1];
    const float* v   = (const float*)d_in[2];
    const float* W_q = (const float*)d_in[3];
    const float* b_q = (const float*)d_in[4];
    const float* W_k = (const float*)d_in[5];
    const float* b_k = (const float*)d_in[6];
    const float* W_v = (const float*)d_in[7];
    const float* b_v = (const float*)d_in[8];
    const float* W_o = (const float*)d_in[9];
    const float* b_o = (const float*)d_in[10];

    constexpr size_t M4 = (size_t)4 * 1024 * 1024;
    constexpr size_t M1 = (size_t)1024 * 1024;

    unsigned short* ob   = (unsigned short*)d_out;
    unsigned short* qb16 = ob;                 // [0,4M)
    unsigned short* wq16 = ob + M4;            // [4M,5M)
    unsigned short* wk16 = ob + M4 + M1;       // [5M,6M)
    unsigned short* wv16 = ob + M4 + 2 * M1;   // [6M,7M)
    unsigned short* d0   = (unsigned short*)d_in[0];
    unsigned short* d1   = (unsigned short*)d_in[1];
    unsigned short* d2   = (unsigned short*)d_in[2];
    unsigned short* kb16 = d0;                 // k bf16 (q fp32 dead after cvtA)
    unsigned short* vb16 = d0 + M4;            // v bf16
    unsigned short* wo16 = (unsigned short*)d_in[3];  // W_o bf16 over W_q fp32
                                               // (dead after cvtA; cvtB is
                                               // stream-ordered after cvtA)
    unsigned short* Qst  = d1;                 // Q stage
    unsigned short* Kst  = d1 + M4;            // K stage
    unsigned short* Vts  = d2;                 // V^T stage
    unsigned short* Ob16 = d2 + M4;            // O stage
    float*          outp = (float*)d_out;

    const dim3 blk(256, 1, 1);
    const int n4 = (int)(M4 / 8), n1 = (int)(M1 / 8);
    const float QSCALE = 0.18033688f;    // 0.125 * log2(e)

    cvt5<<<dim3(2048, 4, 1), blk, 0, stream>>>(
        q, qb16, n4,  W_q, wq16, n1,  W_k, wk16, n1,  W_v, wv16, n1,
        (const float*)nullptr, (unsigned short*)nullptr, 0);
    cvt5<<<dim3(2048, 3, 1), blk, 0, stream>>>(
        k, kb16, n4,  v, vb16, n4,  W_o, wo16, n1,
        nullptr, nullptr, 0, nullptr, nullptr, 0);
    {
        GemmDesc gq{qb16, wq16, b_q, Qst, QSCALE, 0};
        GemmDesc gk{kb16, wk16, b_k, Kst, 1.0f, 0};
        GemmDesc gv{vb16, wv16, b_v, Vts, 1.0f, 1};
        gemm128<<<dim3(8, 32, 3), dim3(512, 1, 1), 0, stream>>>(gq, gk, gv);
    }
    attn_flash<<<dim3(16, 32, 1), dim3(512, 1, 1), 0, stream>>>(Qst, Kst, Vts, Ob16);
    {
        GemmDesc go{Ob16, wo16, b_o, outp, 1.0f, 2};
        gemmO<<<dim3(8, 64, 1), blk, 0, stream>>>(go);
    }
}

// Round 14
// 233.400 us; speedup vs baseline: 1.0639x; 1.0070x over previous
//
#include <hip/hip_runtime.h>

typedef __attribute__((ext_vector_type(8))) short short8;
typedef __attribute__((ext_vector_type(4))) short short4_t;
typedef __attribute__((ext_vector_type(4))) float f32x4;
typedef __attribute__((ext_vector_type(2))) unsigned int u32x2;

#define MFMA_B16(a, b, c) __builtin_amdgcn_mfma_f32_16x16x32_bf16((a), (b), (c), 0, 0, 0)

__device__ __forceinline__ unsigned short f2bf(float x) {
    unsigned u = __builtin_bit_cast(unsigned, x);
    u = (u + 0x7FFFu + ((u >> 16) & 1u)) >> 16;
    return (unsigned short)u;
}

__device__ __forceinline__ void load16_lds(const void* g, void* l) {
    __builtin_amdgcn_global_load_lds(
        (const __attribute__((address_space(1))) unsigned int*)g,
        (__attribute__((address_space(3))) unsigned int*)l, 16, 0, 0);
}

// ---------------- multi-tensor fp32 -> bf16 convert (8 elems/thread) --------
__global__ __launch_bounds__(256) void cvt5(
    const float* s0, unsigned short* d0, int n0,
    const float* s1, unsigned short* d1, int n1,
    const float* s2, unsigned short* d2, int n2,
    const float* s3, unsigned short* d3, int n3,
    const float* s4, unsigned short* d4, int n4)
{
    const float* s; unsigned short* d; int n;
    switch (blockIdx.y) {
        case 0:  s = s0; d = d0; n = n0; break;
        case 1:  s = s1; d = d1; n = n1; break;
        case 2:  s = s2; d = d2; n = n2; break;
        case 3:  s = s3; d = d3; n = n3; break;
        default: s = s4; d = d4; n = n4; break;
    }
    const int i = blockIdx.x * 256 + threadIdx.x;
    if (i < n) {
        const float* p = s + (size_t)i * 8;
        f32x4 x0 = *(const f32x4*)p;
        f32x4 x1 = *(const f32x4*)(p + 4);
        short8 r;
#pragma unroll
        for (int j = 0; j < 4; ++j) r[j] = (short)f2bf(x0[j]);
#pragma unroll
        for (int j = 0; j < 4; ++j) r[j + 4] = (short)f2bf(x1[j]);
        *(short8*)(d + (size_t)i * 8) = r;
    }
}

// -- NT GEMM: 128x128 tile, 8 waves, 3-ring counted-vmcnt, XCD remap ---------
// (round 13, verified: waves-axis 12->24 waves/CU, -5.5us)
struct GemmDesc {
    const unsigned short* A;
    const unsigned short* W;
    const float* bias;
    void* out;
    float scale;
    int mode;   // 0 = bf16 row-major, 1 = V^T per-head [b][h][64][2048], 2 = fp32
};

__global__ __launch_bounds__(512) void gemm128(GemmDesc g0, GemmDesc g1, GemmDesc g2)
{
    constexpr int K = 1024;
    __shared__ union {
        struct { short A[3][128 * 32]; short W[3][128 * 32]; } st;  // 48 KB
        short Lt[128 * 136];                                        // 34.8 KB
    } sm;

    // XCD-chunked bijective remap (requires nwg % 8 == 0; 768 ok)
    const unsigned nwg = gridDim.x * gridDim.y * gridDim.z;
    const unsigned lin = blockIdx.x + gridDim.x * (blockIdx.y + gridDim.y * blockIdx.z);
    const unsigned wl  = (lin & 7u) * (nwg >> 3) + (lin >> 3);
    const unsigned pxy = gridDim.x * gridDim.y;
    const unsigned bz  = wl / pxy;
    const unsigned rm  = wl - bz * pxy;
    const unsigned by  = rm / gridDim.x;
    const unsigned bx  = rm - by * gridDim.x;

    const GemmDesc g = (bz == 0) ? g0 : (bz == 1 ? g1 : g2);
    const int t = threadIdx.x;
    const int lane = t & 63, wave = t >> 6;     // wave 0..7
    const int lanelo = lane & 15, quad = lane >> 4;
    const int wm = wave >> 2, wn = wave & 3;    // 2M x 4N wave grid
    const int bn = bx * 128;
    const int bm = by * 128;

    f32x4 acc[4][2] = {};

    const int r0 = t >> 2;
    const int c0 = ((t & 3) ^ (r0 & 3)) * 8;
    const unsigned short* Ag = g.A + (size_t)(bm + r0) * K + c0;
    const unsigned short* Wg = g.W + (size_t)(bn + r0) * K + c0;
    const int qx = (quad ^ (lanelo & 3)) * 8;   // swizzled read chunk

#define STAGE128(k0, buf)                                             \
    do {                                                              \
        load16_lds(Ag + (k0), sm.st.A[(buf)] + wave * 512);           \
        load16_lds(Wg + (k0), sm.st.W[(buf)] + wave * 512);           \
    } while (0)

    STAGE128(0, 0);
    STAGE128(32, 1);

    int cur = 0;
    for (int k0 = 0; k0 < K; k0 += 32) {
        if (k0 + 32 < K) {
            asm volatile("s_waitcnt vmcnt(2)" ::: "memory");  // tile k0 landed
        } else {
            asm volatile("s_waitcnt vmcnt(0)" ::: "memory");  // last tile
        }
        __builtin_amdgcn_s_barrier();        // all waves: tile-k0 data present,
        asm volatile("" ::: "memory");       // tile-(k0-32) compute finished

        if (k0 + 64 < K) {
            const int nb = (cur + 2 >= 3) ? cur - 1 : cur + 2;
            STAGE128(k0 + 64, nb);           // overwrites tile k0-32 (safe)
        }

        short8 af[4], wf[2];
#pragma unroll
        for (int mt = 0; mt < 4; ++mt)
            af[mt] = *(const short8*)&sm.st.A[cur][(wm * 64 + mt * 16 + lanelo) * 32 + qx];
#pragma unroll
        for (int nt = 0; nt < 2; ++nt)
            wf[nt] = *(const short8*)&sm.st.W[cur][(wn * 32 + nt * 16 + lanelo) * 32 + qx];
#pragma unroll
        for (int mt = 0; mt < 4; ++mt)
#pragma unroll
            for (int nt = 0; nt < 2; ++nt)
                acc[mt][nt] = MFMA_B16(af[mt], wf[nt], acc[mt][nt]);

        asm volatile("" ::: "memory");
        cur = (cur + 1 == 3) ? 0 : cur + 1;
    }
#undef STAGE128

    if (g.mode != 1) {
#pragma unroll
        for (int mt = 0; mt < 4; ++mt) {
#pragma unroll
            for (int nt = 0; nt < 2; ++nt) {
                const int col = bn + wn * 32 + nt * 16 + lanelo;
                const float bs = g.bias[col];
#pragma unroll
                for (int r = 0; r < 4; ++r) {
                    const int row = bm + wm * 64 + mt * 16 + quad * 4 + r;
                    const float val = (acc[mt][nt][r] + bs) * g.scale;
                    if (g.mode == 2)
                        ((float*)g.out)[(size_t)row * K + col] = val;
                    else
                        ((unsigned short*)g.out)[(size_t)row * K + col] = f2bf(val);
                }
            }
        }
    } else {
        __syncthreads();   // staging reads done before Lt (aliases st) is written
#pragma unroll
        for (int mt = 0; mt < 4; ++mt) {
#pragma unroll
            for (int nt = 0; nt < 2; ++nt) {
                const int nl = wn * 32 + nt * 16 + lanelo;
                const float bs = g.bias[bn + nl];
                short4_t pk;
#pragma unroll
                for (int r = 0; r < 4; ++r) pk[r] = (short)f2bf(acc[mt][nt][r] + bs);
                *(short4_t*)&sm.Lt[nl * 136 + wm * 64 + mt * 16 + quad * 4] = pk;
            }
        }
        __syncthreads();
        const int dl = t >> 2;              // 0..127: d-index within tile
        const int sb = (t & 3) * 32;        // 32-short chunk of the s-run
        const int bb = bm >> 11;
        const int s0 = bm & 2047;
        const int hb = bb * 16 + ((bn + dl) >> 6);
        const int dd = (bn + dl) & 63;
        unsigned short* dst = (unsigned short*)g.out +
            ((size_t)hb * 64 + dd) * 2048 + s0 + sb;
#pragma unroll
        for (int j = 0; j < 4; ++j)
            *(short8*)(dst + j * 8) = *(const short8*)&sm.Lt[dl * 136 + sb + j * 8];
    }
}

// -- O-proj GEMM: 64x128 tile, 8 WAVES (was 4), 512 blocks = 16 waves/CU ----
// Round-13 lesson applied to the last 4-wave kernel: same tile, same 36KB
// 3-ring LDS, same grid, but 512 threads. Wave grid 2M x 4N, each wave a
// 32x32 output (4 MFMA/K-step, half the chain). Staging: all 8 waves issue
// one W-call (16 rows each of the 128-row W tile); waves 0-3 additionally
// one A-call (16 rows each of the 64-row A tile). Counted vmcnt is PER-WAVE
// (2 for A-staging waves, 1 for W-only waves -- each wave waits only its own
// loads; the barrier makes all waves' tile-k data visible). 2 blocks/CU x 8
// = 16 waves/CU, double round-13's 8.
__global__ __launch_bounds__(512) void gemmO(GemmDesc g)
{
    constexpr int K = 1024;
    __shared__ struct { short A[3][64 * 32]; short W[3][128 * 32]; } sm;  // 36 KB

    const unsigned nwg = gridDim.x * gridDim.y;       // 512, %8==0
    const unsigned lin = blockIdx.x + gridDim.x * blockIdx.y;
    const unsigned wl  = (lin & 7u) * (nwg >> 3) + (lin >> 3);
    const unsigned by  = wl / gridDim.x;
    const unsigned bx  = wl - by * gridDim.x;

    const int t = threadIdx.x;
    const int lane = t & 63, wave = t >> 6;   // 0..7
    const int lanelo = lane & 15, quad = lane >> 4;
    const int wm = wave >> 2, wn = wave & 3;  // 2M x 4N wave grid
    const int bn = bx * 128;
    const int bm = by * 64;

    f32x4 acc[2][2] = {};

    // staging rows: sr = lane>>2 (16 rows/wave), chunk lane&3; source col
    // pre-swizzled by row&3 (= sr&3, since wave*16 is a multiple of 4).
    const int sr = lane >> 2;
    const int sc = ((lane & 3) ^ (sr & 3)) * 8;
    const unsigned short* Wg = g.W + (size_t)(bn + wave * 16 + sr) * K + sc;
    const unsigned short* Ag = g.A + (size_t)(bm + (wave & 3) * 16 + sr) * K + sc;
    const int qx = (quad ^ (lanelo & 3)) * 8;
    const bool doA = wave < 4;               // wave-uniform

#define STAGEO(k0, buf)                                               \
    do {                                                              \
        load16_lds(Wg + (k0), sm.W[(buf)] + wave * 512);              \
        if (doA) load16_lds(Ag + (k0), sm.A[(buf)] + wave * 512);     \
    } while (0)

    STAGEO(0, 0);
    STAGEO(32, 1);

    int cur = 0;
    for (int k0 = 0; k0 < K; k0 += 32) {
        if (k0 + 32 < K) {
            if (doA) asm volatile("s_waitcnt vmcnt(2)" ::: "memory");
            else     asm volatile("s_waitcnt vmcnt(1)" ::: "memory");
        } else {
            asm volatile("s_waitcnt vmcnt(0)" ::: "memory");
        }
        __builtin_amdgcn_s_barrier();
        asm volatile("" ::: "memory");

        if (k0 + 64 < K) {
            const int nb = (cur + 2 >= 3) ? cur - 1 : cur + 2;
            STAGEO(k0 + 64, nb);             // overwrites tile k0-32 (safe)
        }

        short8 af[2], wf[2];
#pragma unroll
        for (int mt = 0; mt < 2; ++mt)
            af[mt] = *(const short8*)&sm.A[cur][(wm * 32 + mt * 16 + lanelo) * 32 + qx];
#pragma unroll
        for (int nt = 0; nt < 2; ++nt)
            wf[nt] = *(const short8*)&sm.W[cur][(wn * 32 + nt * 16 + lanelo) * 32 + qx];
#pragma unroll
        for (int mt = 0; mt < 2; ++mt)
#pragma unroll
            for (int nt = 0; nt < 2; ++nt)
                acc[mt][nt] = MFMA_B16(af[mt], wf[nt], acc[mt][nt]);

        asm volatile("" ::: "memory");
        cur = (cur + 1 == 3) ? 0 : cur + 1;
    }
#undef STAGEO

#pragma unroll
    for (int mt = 0; mt < 2; ++mt) {
#pragma unroll
        for (int nt = 0; nt < 2; ++nt) {
            const int col = bn + wn * 32 + nt * 16 + lanelo;
            const float bs = g.bias[col];
#pragma unroll
            for (int r = 0; r < 4; ++r) {
                const int row = bm + wm * 32 + mt * 16 + quad * 4 + r;
                ((float*)g.out)[(size_t)row * K + col] = acc[mt][nt][r] + bs;
            }
        }
    }
}

// -- flash attention: 8-wave Q-split, LDS-shared K/V (round 12, verified) ----
__global__ __launch_bounds__(512) void attn_flash(
    const unsigned short* __restrict__ Qs,
    const unsigned short* __restrict__ Ks,
    const unsigned short* __restrict__ Vt,
    unsigned short* __restrict__ Op)
{
    constexpr int S = 2048, D = 1024;
    __shared__ short Kb[2][64 * 64];   // [buf][key][d-swizzled]  8 KB each
    __shared__ short Vb[2][64 * 64];   // [buf][d][key-swizzled]  8 KB each
    __shared__ short Pl[8][16 * 72];   // per-wave P tile [16 q][64 key]

    const int tid    = threadIdx.x;
    const int lane   = tid & 63;
    const int wave   = tid >> 6;          // Q-split slot 0..7
    const int lanelo = lane & 15;
    const int quad   = lane >> 4;

    // XCD-chunked bijective remap: grid (16,32) -> XCD c owns heads [4c,4c+4)
    const unsigned lin = blockIdx.x + 16u * blockIdx.y;
    const unsigned wl  = (lin & 7u) * 64u + (lin >> 3);
    const int qt = (int)(wl & 15u);       // 0..15 (128 q-rows per block)
    const int bh = (int)(wl >> 4);        // 0..31
    const int b  = bh >> 4;
    const int h  = bh & 15;
    const size_t base = (size_t)b * S * D + (size_t)h * 64;
    const unsigned short* Vh = Vt + (size_t)bh * 64 * S;
    short* Plw = Pl[wave];
    const int qrow0 = qt * 128 + wave * 16;

    short8 aq[2];
#pragma unroll
    for (int ks = 0; ks < 2; ++ks)
        aq[ks] = *(const short8*)(Qs + base +
            (size_t)(qrow0 + lanelo) * D + ks * 32 + quad * 8);

    f32x4 oacc[4] = {};
    float lac = 0.0f;                     // per-lane partial l for q = lanelo

    const int lr = lane >> 3;
    const int lc = (((lane & 7) ^ lr) * 8);
    const unsigned short* kg = Ks + base + (size_t)(wave * 8 + lr) * D + lc;
    const unsigned short* vg = Vh + (size_t)(wave * 8 + lr) * S + lc;

    load16_lds(kg, &Kb[0][wave * 512]);
    load16_lds(vg, &Vb[0][wave * 512]);
    __syncthreads();

    int cur = 0;
    for (int kt = 0; kt < 32; ++kt) {
        if (kt < 31) {
            load16_lds(kg + (size_t)(kt + 1) * 64 * D, &Kb[cur ^ 1][wave * 512]);
            load16_lds(vg + (kt + 1) * 64, &Vb[cur ^ 1][wave * 512]);
        }

        short8 kfr[2][4];
#pragma unroll
        for (int ks = 0; ks < 2; ++ks)
#pragma unroll
            for (int nk = 0; nk < 4; ++nk) {
                const int k = nk * 16 + lanelo;
                kfr[ks][nk] = *(const short8*)&Kb[cur][k * 64 +
                    ((ks * 32 + quad * 8) ^ ((k & 7) << 3))];
            }

        f32x4 sv[4] = {};
        __builtin_amdgcn_s_setprio(1);
#pragma unroll
        for (int ks = 0; ks < 2; ++ks)
#pragma unroll
            for (int nt = 0; nt < 4; ++nt)
                sv[nt] = MFMA_B16(kfr[ks][nt], aq[ks], sv[nt]);
        __builtin_amdgcn_s_setprio(0);

#pragma unroll
        for (int nt = 0; nt < 4; ++nt) {
            unsigned u[4];
#pragma unroll
            for (int r = 0; r < 4; ++r) {
                const float p = exp2f(sv[nt][r]);
                const unsigned tr = __builtin_bit_cast(unsigned, p) & 0xFFFF0000u;
                lac += __builtin_bit_cast(float, tr);
                u[r] = tr;
            }
            u32x2 pk;
            pk[0] = __builtin_amdgcn_perm(u[1], u[0], 0x07060302u);
            pk[1] = __builtin_amdgcn_perm(u[3], u[2], 0x07060302u);
            *(u32x2*)&Plw[lanelo * 72 + nt * 16 + quad * 4] = pk;
        }

        __builtin_amdgcn_wave_barrier();   // pin DS order: P writes before reads

        __builtin_amdgcn_s_setprio(1);
#pragma unroll
        for (int ks = 0; ks < 2; ++ks) {
            short8 vfr[4];
#pragma unroll
            for (int nt = 0; nt < 4; ++nt) {
                const int d = nt * 16 + lanelo;
                vfr[nt] = *(const short8*)&Vb[cur][d * 64 +
                    ((ks * 32 + quad * 8) ^ ((d & 7) << 3))];
            }
            const short8 ap = *(const short8*)&Plw[lanelo * 72 + ks * 32 + quad * 8];
#pragma unroll
            for (int nt = 0; nt < 4; ++nt)
                oacc[nt] = MFMA_B16(ap, vfr[nt], oacc[nt]);
        }
        __builtin_amdgcn_s_setprio(0);

        __builtin_amdgcn_wave_barrier();   // pin DS order: reads before next writes

        if (kt < 31) {
            __syncthreads();
            cur ^= 1;
        }
    }

    float l = lac;
    l += __shfl_xor(l, 16);
    l += __shfl_xor(l, 32);

#pragma unroll
    for (int r = 0; r < 4; ++r) {
        const float inv = 1.0f / __shfl(l, quad * 4 + r);
        const int row = qrow0 + quad * 4 + r;
#pragma unroll
        for (int nt = 0; nt < 4; ++nt)
            Op[base + (size_t)row * D + nt * 16 + lanelo] = f2bf(oacc[nt][r] * inv);
    }
}

extern "C" void kernel_launch(void* const* d_in, const int* in_sizes, int n_in,
                              void* d_out, int out_size, void* d_ws, size_t ws_size,
                              hipStream_t stream) {
    const float* q   = (const float*)d_in[0];
    const float* k   = (const float*)d_in[1];
    const float* v   = (const float*)d_in[2];
    const float* W_q = (const float*)d_in[3];
    const float* b_q = (const float*)d_in[4];
    const float* W_k = (const float*)d_in[5];
    const float* b_k = (const float*)d_in[6];
    const float* W_v = (const float*)d_in[7];
    const float* b_v = (const float*)d_in[8];
    const float* W_o = (const float*)d_in[9];
    const float* b_o = (const float*)d_in[10];

    constexpr size_t M4 = (size_t)4 * 1024 * 1024;
    constexpr size_t M1 = (size_t)1024 * 1024;

    unsigned short* ob   = (unsigned short*)d_out;
    unsigned short* qb16 = ob;                 // [0,4M)
    unsigned short* wq16 = ob + M4;            // [4M,5M)
    unsigned short* wk16 = ob + M4 + M1;       // [5M,6M)
    unsigned short* wv16 = ob + M4 + 2 * M1;   // [6M,7M)
    unsigned short* d0   = (unsigned short*)d_in[0];
    unsigned short* d1   = (unsigned short*)d_in[1];
    unsigned short* d2   = (unsigned short*)d_in[2];
    unsigned short* kb16 = d0;                 // k bf16 (q fp32 dead after cvtA)
    unsigned short* vb16 = d0 + M4;            // v bf16
    unsigned short* wo16 = (unsigned short*)d_in[3];  // W_o bf16 over W_q fp32
                                               // (dead after cvtA; cvtB is
                                               // stream-ordered after cvtA)
    unsigned short* Qst  = d1;                 // Q stage
    unsigned short* Kst  = d1 + M4;            // K stage
    unsigned short* Vts  = d2;                 // V^T stage
    unsigned short* Ob16 = d2 + M4;            // O stage
    float*          outp = (float*)d_out;

    const dim3 blk(256, 1, 1);
    const int n4 = (int)(M4 / 8), n1 = (int)(M1 / 8);
    const float QSCALE = 0.18033688f;    // 0.125 * log2(e)

    cvt5<<<dim3(2048, 4, 1), blk, 0, stream>>>(
        q, qb16, n4,  W_q, wq16, n1,  W_k, wk16, n1,  W_v, wv16, n1,
        (const float*)nullptr, (unsigned short*)nullptr, 0);
    cvt5<<<dim3(2048, 3, 1), blk, 0, stream>>>(
        k, kb16, n4,  v, vb16, n4,  W_o, wo16, n1,
        nullptr, nullptr, 0, nullptr, nullptr, 0);
    {
        GemmDesc gq{qb16, wq16, b_q, Qst, QSCALE, 0};
        GemmDesc gk{kb16, wk16, b_k, Kst, 1.0f, 0};
        GemmDesc gv{vb16, wv16, b_v, Vts, 1.0f, 1};
        gemm128<<<dim3(8, 32, 3), dim3(512, 1, 1), 0, stream>>>(gq, gk, gv);
    }
    attn_flash<<<dim3(16, 32, 1), dim3(512, 1, 1), 0, stream>>>(Qst, Kst, Vts, Ob16);
    {
        GemmDesc go{Ob16, wo16, b_o, outp, 1.0f, 2};
        gemmO<<<dim3(8, 64, 1), dim3(512, 1, 1), 0, stream>>>(go);
    }
}

// Round 15
// 228.619 us; speedup vs baseline: 1.0861x; 1.0209x over previous
//
#include <hip/hip_runtime.h>

typedef __attribute__((ext_vector_type(8))) short short8;
typedef __attribute__((ext_vector_type(4))) short short4_t;
typedef __attribute__((ext_vector_type(4))) float f32x4;
typedef __attribute__((ext_vector_type(2))) unsigned int u32x2;

#define MFMA_B16(a, b, c) __builtin_amdgcn_mfma_f32_16x16x32_bf16((a), (b), (c), 0, 0, 0)

__device__ __forceinline__ unsigned short f2bf(float x) {
    unsigned u = __builtin_bit_cast(unsigned, x);
    u = (u + 0x7FFFu + ((u >> 16) & 1u)) >> 16;
    return (unsigned short)u;
}

__device__ __forceinline__ void load16_lds(const void* g, void* l) {
    __builtin_amdgcn_global_load_lds(
        (const __attribute__((address_space(1))) unsigned int*)g,
        (__attribute__((address_space(3))) unsigned int*)l, 16, 0, 0);
}

// ---------------- multi-tensor fp32 -> bf16 convert (8 elems/thread) --------
__device__ __forceinline__ void cvt_body(const float* s, unsigned short* d, int n) {
    const int i = blockIdx.x * 256 + threadIdx.x;
    if (i < n) {
        const float* p = s + (size_t)i * 8;
        f32x4 x0 = *(const f32x4*)p;
        f32x4 x1 = *(const f32x4*)(p + 4);
        short8 r;
#pragma unroll
        for (int j = 0; j < 4; ++j) r[j] = (short)f2bf(x0[j]);
#pragma unroll
        for (int j = 0; j < 4; ++j) r[j + 4] = (short)f2bf(x1[j]);
        *(short8*)(d + (size_t)i * 8) = r;
    }
}

__global__ __launch_bounds__(256) void cvt5(
    const float* s0, unsigned short* d0, int n0,
    const float* s1, unsigned short* d1, int n1,
    const float* s2, unsigned short* d2, int n2,
    const float* s3, unsigned short* d3, int n3,
    const float* s4, unsigned short* d4, int n4)
{
    const float* s; unsigned short* d; int n;
    switch (blockIdx.y) {
        case 0:  s = s0; d = d0; n = n0; break;
        case 1:  s = s1; d = d1; n = n1; break;
        case 2:  s = s2; d = d2; n = n2; break;
        case 3:  s = s3; d = d3; n = n3; break;
        default: s = s4; d = d4; n = n4; break;
    }
    cvt_body(s, d, n);
}

// 7-slot variant: all conversions in ONE launch (requires non-aliasing
// destinations -- kb16/vb16/wo16 live in d_ws on this path).
__global__ __launch_bounds__(256) void cvt7(
    const float* s0, unsigned short* d0, int n0,
    const float* s1, unsigned short* d1, int n1,
    const float* s2, unsigned short* d2, int n2,
    const float* s3, unsigned short* d3, int n3,
    const float* s4, unsigned short* d4, int n4,
    const float* s5, unsigned short* d5, int n5,
    const float* s6, unsigned short* d6, int n6)
{
    const float* s; unsigned short* d; int n;
    switch (blockIdx.y) {
        case 0:  s = s0; d = d0; n = n0; break;
        case 1:  s = s1; d = d1; n = n1; break;
        case 2:  s = s2; d = d2; n = n2; break;
        case 3:  s = s3; d = d3; n = n3; break;
        case 4:  s = s4; d = d4; n = n4; break;
        case 5:  s = s5; d = d5; n = n5; break;
        default: s = s6; d = d6; n = n6; break;
    }
    cvt_body(s, d, n);
}

// -- NT GEMM: 128x128 tile, 8 waves, 3-ring counted-vmcnt, XCD remap ---------
// (round 13, verified)
struct GemmDesc {
    const unsigned short* A;
    const unsigned short* W;
    const float* bias;
    void* out;
    float scale;
    int mode;   // 0 = bf16 row-major, 1 = V^T per-head [b][h][64][2048], 2 = fp32
};

__global__ __launch_bounds__(512) void gemm128(GemmDesc g0, GemmDesc g1, GemmDesc g2)
{
    constexpr int K = 1024;
    __shared__ union {
        struct { short A[3][128 * 32]; short W[3][128 * 32]; } st;  // 48 KB
        short Lt[128 * 136];                                        // 34.8 KB
    } sm;

    // XCD-chunked bijective remap (requires nwg % 8 == 0; 768 ok)
    const unsigned nwg = gridDim.x * gridDim.y * gridDim.z;
    const unsigned lin = blockIdx.x + gridDim.x * (blockIdx.y + gridDim.y * blockIdx.z);
    const unsigned wl  = (lin & 7u) * (nwg >> 3) + (lin >> 3);
    const unsigned pxy = gridDim.x * gridDim.y;
    const unsigned bz  = wl / pxy;
    const unsigned rm  = wl - bz * pxy;
    const unsigned by  = rm / gridDim.x;
    const unsigned bx  = rm - by * gridDim.x;

    const GemmDesc g = (bz == 0) ? g0 : (bz == 1 ? g1 : g2);
    const int t = threadIdx.x;
    const int lane = t & 63, wave = t >> 6;     // wave 0..7
    const int lanelo = lane & 15, quad = lane >> 4;
    const int wm = wave >> 2, wn = wave & 3;    // 2M x 4N wave grid
    const int bn = bx * 128;
    const int bm = by * 128;

    f32x4 acc[4][2] = {};

    const int r0 = t >> 2;
    const int c0 = ((t & 3) ^ (r0 & 3)) * 8;
    const unsigned short* Ag = g.A + (size_t)(bm + r0) * K + c0;
    const unsigned short* Wg = g.W + (size_t)(bn + r0) * K + c0;
    const int qx = (quad ^ (lanelo & 3)) * 8;   // swizzled read chunk

#define STAGE128(k0, buf)                                             \
    do {                                                              \
        load16_lds(Ag + (k0), sm.st.A[(buf)] + wave * 512);           \
        load16_lds(Wg + (k0), sm.st.W[(buf)] + wave * 512);           \
    } while (0)

    STAGE128(0, 0);
    STAGE128(32, 1);

    int cur = 0;
    for (int k0 = 0; k0 < K; k0 += 32) {
        if (k0 + 32 < K) {
            asm volatile("s_waitcnt vmcnt(2)" ::: "memory");  // tile k0 landed
        } else {
            asm volatile("s_waitcnt vmcnt(0)" ::: "memory");  // last tile
        }
        __builtin_amdgcn_s_barrier();        // all waves: tile-k0 data present,
        asm volatile("" ::: "memory");       // tile-(k0-32) compute finished

        if (k0 + 64 < K) {
            const int nb = (cur + 2 >= 3) ? cur - 1 : cur + 2;
            STAGE128(k0 + 64, nb);           // overwrites tile k0-32 (safe)
        }

        short8 af[4], wf[2];
#pragma unroll
        for (int mt = 0; mt < 4; ++mt)
            af[mt] = *(const short8*)&sm.st.A[cur][(wm * 64 + mt * 16 + lanelo) * 32 + qx];
#pragma unroll
        for (int nt = 0; nt < 2; ++nt)
            wf[nt] = *(const short8*)&sm.st.W[cur][(wn * 32 + nt * 16 + lanelo) * 32 + qx];
#pragma unroll
        for (int mt = 0; mt < 4; ++mt)
#pragma unroll
            for (int nt = 0; nt < 2; ++nt)
                acc[mt][nt] = MFMA_B16(af[mt], wf[nt], acc[mt][nt]);

        asm volatile("" ::: "memory");
        cur = (cur + 1 == 3) ? 0 : cur + 1;
    }
#undef STAGE128

    if (g.mode != 1) {
#pragma unroll
        for (int mt = 0; mt < 4; ++mt) {
#pragma unroll
            for (int nt = 0; nt < 2; ++nt) {
                const int col = bn + wn * 32 + nt * 16 + lanelo;
                const float bs = g.bias[col];
#pragma unroll
                for (int r = 0; r < 4; ++r) {
                    const int row = bm + wm * 64 + mt * 16 + quad * 4 + r;
                    const float val = (acc[mt][nt][r] + bs) * g.scale;
                    if (g.mode == 2)
                        ((float*)g.out)[(size_t)row * K + col] = val;
                    else
                        ((unsigned short*)g.out)[(size_t)row * K + col] = f2bf(val);
                }
            }
        }
    } else {
        __syncthreads();   // staging reads done before Lt (aliases st) is written
#pragma unroll
        for (int mt = 0; mt < 4; ++mt) {
#pragma unroll
            for (int nt = 0; nt < 2; ++nt) {
                const int nl = wn * 32 + nt * 16 + lanelo;
                const float bs = g.bias[bn + nl];
                short4_t pk;
#pragma unroll
                for (int r = 0; r < 4; ++r) pk[r] = (short)f2bf(acc[mt][nt][r] + bs);
                *(short4_t*)&sm.Lt[nl * 136 + wm * 64 + mt * 16 + quad * 4] = pk;
            }
        }
        __syncthreads();
        const int dl = t >> 2;              // 0..127: d-index within tile
        const int sb = (t & 3) * 32;        // 32-short chunk of the s-run
        const int bb = bm >> 11;
        const int s0 = bm & 2047;
        const int hb = bb * 16 + ((bn + dl) >> 6);
        const int dd = (bn + dl) & 63;
        unsigned short* dst = (unsigned short*)g.out +
            ((size_t)hb * 64 + dd) * 2048 + s0 + sb;
#pragma unroll
        for (int j = 0; j < 4; ++j)
            *(short8*)(dst + j * 8) = *(const short8*)&sm.Lt[dl * 136 + sb + j * 8];
    }
}

// -- O-proj GEMM: 64x128 tile, 8 waves, 512 blocks (round 14, verified) ------
__global__ __launch_bounds__(512) void gemmO(GemmDesc g)
{
    constexpr int K = 1024;
    __shared__ struct { short A[3][64 * 32]; short W[3][128 * 32]; } sm;  // 36 KB

    const unsigned nwg = gridDim.x * gridDim.y;       // 512, %8==0
    const unsigned lin = blockIdx.x + gridDim.x * blockIdx.y;
    const unsigned wl  = (lin & 7u) * (nwg >> 3) + (lin >> 3);
    const unsigned by  = wl / gridDim.x;
    const unsigned bx  = wl - by * gridDim.x;

    const int t = threadIdx.x;
    const int lane = t & 63, wave = t >> 6;   // 0..7
    const int lanelo = lane & 15, quad = lane >> 4;
    const int wm = wave >> 2, wn = wave & 3;  // 2M x 4N wave grid
    const int bn = bx * 128;
    const int bm = by * 64;

    f32x4 acc[2][2] = {};

    const int sr = lane >> 2;
    const int sc = ((lane & 3) ^ (sr & 3)) * 8;
    const unsigned short* Wg = g.W + (size_t)(bn + wave * 16 + sr) * K + sc;
    const unsigned short* Ag = g.A + (size_t)(bm + (wave & 3) * 16 + sr) * K + sc;
    const int qx = (quad ^ (lanelo & 3)) * 8;
    const bool doA = wave < 4;               // wave-uniform

#define STAGEO(k0, buf)                                               \
    do {                                                              \
        load16_lds(Wg + (k0), sm.W[(buf)] + wave * 512);              \
        if (doA) load16_lds(Ag + (k0), sm.A[(buf)] + wave * 512);     \
    } while (0)

    STAGEO(0, 0);
    STAGEO(32, 1);

    int cur = 0;
    for (int k0 = 0; k0 < K; k0 += 32) {
        if (k0 + 32 < K) {
            if (doA) asm volatile("s_waitcnt vmcnt(2)" ::: "memory");
            else     asm volatile("s_waitcnt vmcnt(1)" ::: "memory");
        } else {
            asm volatile("s_waitcnt vmcnt(0)" ::: "memory");
        }
        __builtin_amdgcn_s_barrier();
        asm volatile("" ::: "memory");

        if (k0 + 64 < K) {
            const int nb = (cur + 2 >= 3) ? cur - 1 : cur + 2;
            STAGEO(k0 + 64, nb);             // overwrites tile k0-32 (safe)
        }

        short8 af[2], wf[2];
#pragma unroll
        for (int mt = 0; mt < 2; ++mt)
            af[mt] = *(const short8*)&sm.A[cur][(wm * 32 + mt * 16 + lanelo) * 32 + qx];
#pragma unroll
        for (int nt = 0; nt < 2; ++nt)
            wf[nt] = *(const short8*)&sm.W[cur][(wn * 32 + nt * 16 + lanelo) * 32 + qx];
#pragma unroll
        for (int mt = 0; mt < 2; ++mt)
#pragma unroll
            for (int nt = 0; nt < 2; ++nt)
                acc[mt][nt] = MFMA_B16(af[mt], wf[nt], acc[mt][nt]);

        asm volatile("" ::: "memory");
        cur = (cur + 1 == 3) ? 0 : cur + 1;
    }
#undef STAGEO

#pragma unroll
    for (int mt = 0; mt < 2; ++mt) {
#pragma unroll
        for (int nt = 0; nt < 2; ++nt) {
            const int col = bn + wn * 32 + nt * 16 + lanelo;
            const float bs = g.bias[col];
#pragma unroll
            for (int r = 0; r < 4; ++r) {
                const int row = bm + wm * 32 + mt * 16 + quad * 4 + r;
                ((float*)g.out)[(size_t)row * K + col] = acc[mt][nt][r] + bs;
            }
        }
    }
}

// -- flash attention: 8-wave Q-split, LDS-shared K/V, SPLIT l-accumulators ---
// Round-14 change: the l sum was ONE register receiving 16 dependent FADDs
// per iteration (~64 cyc of pure serial latency, longer than the QK MFMA
// phase; f32 adds can't be reassociated by the compiler without fast-math).
// Split into 4 accumulators (one per nt block), merged in the epilogue:
// serial chain per iter drops 16 -> 4 adds. Everything else = round 12.
__global__ __launch_bounds__(512) void attn_flash(
    const unsigned short* __restrict__ Qs,
    const unsigned short* __restrict__ Ks,
    const unsigned short* __restrict__ Vt,
    unsigned short* __restrict__ Op)
{
    constexpr int S = 2048, D = 1024;
    __shared__ short Kb[2][64 * 64];   // [buf][key][d-swizzled]  8 KB each
    __shared__ short Vb[2][64 * 64];   // [buf][d][key-swizzled]  8 KB each
    __shared__ short Pl[8][16 * 72];   // per-wave P tile [16 q][64 key]

    const int tid    = threadIdx.x;
    const int lane   = tid & 63;
    const int wave   = tid >> 6;          // Q-split slot 0..7
    const int lanelo = lane & 15;
    const int quad   = lane >> 4;

    // XCD-chunked bijective remap: grid (16,32) -> XCD c owns heads [4c,4c+4)
    const unsigned lin = blockIdx.x + 16u * blockIdx.y;
    const unsigned wl  = (lin & 7u) * 64u + (lin >> 3);
    const int qt = (int)(wl & 15u);       // 0..15 (128 q-rows per block)
    const int bh = (int)(wl >> 4);        // 0..31
    const int b  = bh >> 4;
    const int h  = bh & 15;
    const size_t base = (size_t)b * S * D + (size_t)h * 64;
    const unsigned short* Vh = Vt + (size_t)bh * 64 * S;
    short* Plw = Pl[wave];
    const int qrow0 = qt * 128 + wave * 16;

    short8 aq[2];
#pragma unroll
    for (int ks = 0; ks < 2; ++ks)
        aq[ks] = *(const short8*)(Qs + base +
            (size_t)(qrow0 + lanelo) * D + ks * 32 + quad * 8);

    f32x4 oacc[4] = {};
    f32x4 lac4 = {};                      // 4 independent l partials (per nt)

    const int lr = lane >> 3;
    const int lc = (((lane & 7) ^ lr) * 8);
    const unsigned short* kg = Ks + base + (size_t)(wave * 8 + lr) * D + lc;
    const unsigned short* vg = Vh + (size_t)(wave * 8 + lr) * S + lc;

    load16_lds(kg, &Kb[0][wave * 512]);
    load16_lds(vg, &Vb[0][wave * 512]);
    __syncthreads();

    int cur = 0;
    for (int kt = 0; kt < 32; ++kt) {
        if (kt < 31) {
            load16_lds(kg + (size_t)(kt + 1) * 64 * D, &Kb[cur ^ 1][wave * 512]);
            load16_lds(vg + (kt + 1) * 64, &Vb[cur ^ 1][wave * 512]);
        }

        short8 kfr[2][4];
#pragma unroll
        for (int ks = 0; ks < 2; ++ks)
#pragma unroll
            for (int nk = 0; nk < 4; ++nk) {
                const int k = nk * 16 + lanelo;
                kfr[ks][nk] = *(const short8*)&Kb[cur][k * 64 +
                    ((ks * 32 + quad * 8) ^ ((k & 7) << 3))];
            }

        f32x4 sv[4] = {};
        __builtin_amdgcn_s_setprio(1);
#pragma unroll
        for (int ks = 0; ks < 2; ++ks)
#pragma unroll
            for (int nt = 0; nt < 4; ++nt)
                sv[nt] = MFMA_B16(kfr[ks][nt], aq[ks], sv[nt]);
        __builtin_amdgcn_s_setprio(0);

#pragma unroll
        for (int nt = 0; nt < 4; ++nt) {
            unsigned u[4];
#pragma unroll
            for (int r = 0; r < 4; ++r) {
                const float p = exp2f(sv[nt][r]);
                const unsigned tr = __builtin_bit_cast(unsigned, p) & 0xFFFF0000u;
                lac4[nt] += __builtin_bit_cast(float, tr);
                u[r] = tr;
            }
            u32x2 pk;
            pk[0] = __builtin_amdgcn_perm(u[1], u[0], 0x07060302u);
            pk[1] = __builtin_amdgcn_perm(u[3], u[2], 0x07060302u);
            *(u32x2*)&Plw[lanelo * 72 + nt * 16 + quad * 4] = pk;
        }

        __builtin_amdgcn_wave_barrier();   // pin DS order: P writes before reads

        __builtin_amdgcn_s_setprio(1);
#pragma unroll
        for (int ks = 0; ks < 2; ++ks) {
            short8 vfr[4];
#pragma unroll
            for (int nt = 0; nt < 4; ++nt) {
                const int d = nt * 16 + lanelo;
                vfr[nt] = *(const short8*)&Vb[cur][d * 64 +
                    ((ks * 32 + quad * 8) ^ ((d & 7) << 3))];
            }
            const short8 ap = *(const short8*)&Plw[lanelo * 72 + ks * 32 + quad * 8];
#pragma unroll
            for (int nt = 0; nt < 4; ++nt)
                oacc[nt] = MFMA_B16(ap, vfr[nt], oacc[nt]);
        }
        __builtin_amdgcn_s_setprio(0);

        __builtin_amdgcn_wave_barrier();   // pin DS order: reads before next writes

        if (kt < 31) {
            __syncthreads();
            cur ^= 1;
        }
    }

    float l = (lac4[0] + lac4[1]) + (lac4[2] + lac4[3]);
    l += __shfl_xor(l, 16);
    l += __shfl_xor(l, 32);

#pragma unroll
    for (int r = 0; r < 4; ++r) {
        const float inv = 1.0f / __shfl(l, quad * 4 + r);
        const int row = qrow0 + quad * 4 + r;
#pragma unroll
        for (int nt = 0; nt < 4; ++nt)
            Op[base + (size_t)row * D + nt * 16 + lanelo] = f2bf(oacc[nt][r] * inv);
    }
}

extern "C" void kernel_launch(void* const* d_in, const int* in_sizes, int n_in,
                              void* d_out, int out_size, void* d_ws, size_t ws_size,
                              hipStream_t stream) {
    const float* q   = (const float*)d_in[0];
    const float* k   = (const float*)d_in[1];
    const float* v   = (const float*)d_in[2];
    const float* W_q = (const float*)d_in[3];
    const float* b_q = (const float*)d_in[4];
    const float* W_k = (const float*)d_in[5];
    const float* b_k = (const float*)d_in[6];
    const float* W_v = (const float*)d_in[7];
    const float* b_v = (const float*)d_in[8];
    const float* W_o = (const float*)d_in[9];
    const float* b_o = (const float*)d_in[10];

    constexpr size_t M4 = (size_t)4 * 1024 * 1024;
    constexpr size_t M1 = (size_t)1024 * 1024;

    unsigned short* ob   = (unsigned short*)d_out;
    unsigned short* qb16 = ob;                 // [0,4M)
    unsigned short* wq16 = ob + M4;            // [4M,5M)
    unsigned short* wk16 = ob + M4 + M1;       // [5M,6M)
    unsigned short* wv16 = ob + M4 + 2 * M1;   // [6M,7M)
    unsigned short* d0   = (unsigned short*)d_in[0];
    unsigned short* d1   = (unsigned short*)d_in[1];
    unsigned short* d2   = (unsigned short*)d_in[2];
    unsigned short* Qst  = d1;                 // Q stage
    unsigned short* Kst  = d1 + M4;            // K stage
    unsigned short* Vts  = d2;                 // V^T stage
    unsigned short* Ob16 = d2 + M4;            // O stage
    float*          outp = (float*)d_out;

    const dim3 blk(256, 1, 1);
    const int n4 = (int)(M4 / 8), n1 = (int)(M1 / 8);
    const float QSCALE = 0.18033688f;    // 0.125 * log2(e)

    unsigned short* kb16;
    unsigned short* vb16;
    unsigned short* wo16;

    // Single-launch cvt when the workspace can host kb16/vb16/wo16 (18 MB).
    // All 7 slots then read only pristine inputs -> no intra-launch aliasing.
    if (ws_size >= (2 * M4 + M1) * sizeof(unsigned short)) {
        unsigned short* ws = (unsigned short*)d_ws;
        kb16 = ws;                 // k bf16
        vb16 = ws + M4;            // v bf16
        wo16 = ws + 2 * M4;        // W_o bf16
        cvt7<<<dim3(2048, 7, 1), blk, 0, stream>>>(
            q, qb16, n4,  k, kb16, n4,  v, vb16, n4,
            W_q, wq16, n1,  W_k, wk16, n1,  W_v, wv16, n1,  W_o, wo16, n1);
    } else {
        // Fallback: two launches with the round-14 aliasing layout (kb16/vb16
        // over q's fp32 -- dead after cvtA; wo16 over W_q fp32 -- dead after
        // cvtA; cvtB is stream-ordered after cvtA).
        kb16 = d0;
        vb16 = d0 + M4;
        wo16 = (unsigned short*)d_in[3];
        cvt5<<<dim3(2048, 4, 1), blk, 0, stream>>>(
            q, qb16, n4,  W_q, wq16, n1,  W_k, wk16, n1,  W_v, wv16, n1,
            (const float*)nullptr, (unsigned short*)nullptr, 0);
        cvt5<<<dim3(2048, 3, 1), blk, 0, stream>>>(
            k, kb16, n4,  v, vb16, n4,  W_o, wo16, n1,
            nullptr, nullptr, 0, nullptr, nullptr, 0);
    }

    {
        GemmDesc gq{qb16, wq16, b_q, Qst, QSCALE, 0};
        GemmDesc gk{kb16, wk16, b_k, Kst, 1.0f, 0};
        GemmDesc gv{vb16, wv16, b_v, Vts, 1.0f, 1};
        gemm128<<<dim3(8, 32, 3), dim3(512, 1, 1), 0, stream>>>(gq, gk, gv);
    }
    attn_flash<<<dim3(16, 32, 1), dim3(512, 1, 1), 0, stream>>>(Qst, Kst, Vts, Ob16);
    {
        GemmDesc go{Ob16, wo16, b_o, outp, 1.0f, 2};
        gemmO<<<dim3(8, 64, 1), dim3(512, 1, 1), 0, stream>>>(go);
    }
}